// Round 1
// baseline (452.172 us; speedup 1.0000x reference)
//
#include <hip/hip_runtime.h>
#include <hip/hip_bf16.h>

#define L_SEQ 4096
#define E_DIM 512
#define NHEAD 8
#define DHEAD 64
#define NBATCH 4
#define NROWS (NBATCH * L_SEQ)   // 16384

typedef short bf16x8 __attribute__((ext_vector_type(8)));
typedef float f32x4 __attribute__((ext_vector_type(4)));

__device__ __forceinline__ float bf2f(ushort u) {
    union { float f; unsigned int i; } x;
    x.i = ((unsigned int)u) << 16;
    return x.f;
}
__device__ __forceinline__ ushort f2bf(float f) {
    unsigned int u = __float_as_uint(f);
    unsigned int r = 0x7fffu + ((u >> 16) & 1u);
    u += r;
    return (ushort)(u >> 16);
}

// ---------------- fp32 -> bf16 conversion ----------------
__global__ void convert_kernel(const float* __restrict__ in, ushort* __restrict__ out, int n4) {
    int stride = gridDim.x * blockDim.x;
    for (int i = blockIdx.x * blockDim.x + threadIdx.x; i < n4; i += stride) {
        float4 f = reinterpret_cast<const float4*>(in)[i];
        ushort4 o;
        o.x = f2bf(f.x); o.y = f2bf(f.y); o.z = f2bf(f.z); o.w = f2bf(f.w);
        reinterpret_cast<ushort4*>(out)[i] = o;
    }
}

// ---------------- MFMA GEMM: out = A(16384x512) @ W^T(512x512) + bias ----------------
// MODE 0: relu, then write val*cos -> outC (bf16) and val*sin -> outS (bf16)
// MODE 1: write val -> outC (bf16)
// MODE 2: write val -> outF (fp32)
template<int MODE>
__global__ __launch_bounds__(256) void gemm_kernel(
    const ushort* __restrict__ A,
    const ushort* __restrict__ W,
    const float* __restrict__ bias,
    ushort* __restrict__ outC,
    ushort* __restrict__ outS,
    float* __restrict__ outF)
{
    __shared__ ushort As[128][32];
    __shared__ ushort Bs[128][32];
    const int tid = threadIdx.x;
    const int lane = tid & 63;
    const int wid = tid >> 6;
    const int wr = wid >> 1, wc = wid & 1;
    const int rowBase = blockIdx.x * 128;
    const int colBase = blockIdx.y * 128;

    f32x4 acc[4][4];
#pragma unroll
    for (int m = 0; m < 4; ++m)
#pragma unroll
        for (int n = 0; n < 4; ++n)
            acc[m][n] = (f32x4){0.f, 0.f, 0.f, 0.f};

    const int lr = tid >> 2;          // 0..63
    const int lc = (tid & 3) * 8;     // 0,8,16,24
    const int frow = lane & 15;
    const int fk = (lane >> 4) * 8;

    for (int k0 = 0; k0 < E_DIM; k0 += 32) {
        *reinterpret_cast<uint4*>(&As[lr][lc]) =
            *reinterpret_cast<const uint4*>(&A[(size_t)(rowBase + lr) * E_DIM + k0 + lc]);
        *reinterpret_cast<uint4*>(&As[lr + 64][lc]) =
            *reinterpret_cast<const uint4*>(&A[(size_t)(rowBase + lr + 64) * E_DIM + k0 + lc]);
        *reinterpret_cast<uint4*>(&Bs[lr][lc]) =
            *reinterpret_cast<const uint4*>(&W[(size_t)(colBase + lr) * E_DIM + k0 + lc]);
        *reinterpret_cast<uint4*>(&Bs[lr + 64][lc]) =
            *reinterpret_cast<const uint4*>(&W[(size_t)(colBase + lr + 64) * E_DIM + k0 + lc]);
        __syncthreads();
        bf16x8 af[4], bfr[4];
#pragma unroll
        for (int m = 0; m < 4; ++m)
            af[m] = *reinterpret_cast<const bf16x8*>(&As[wr * 64 + m * 16 + frow][fk]);
#pragma unroll
        for (int n = 0; n < 4; ++n)
            bfr[n] = *reinterpret_cast<const bf16x8*>(&Bs[wc * 64 + n * 16 + frow][fk]);
#pragma unroll
        for (int m = 0; m < 4; ++m)
#pragma unroll
            for (int n = 0; n < 4; ++n)
                acc[m][n] = __builtin_amdgcn_mfma_f32_16x16x32_bf16(af[m], bfr[n], acc[m][n], 0, 0, 0);
        __syncthreads();
    }

#pragma unroll
    for (int m = 0; m < 4; ++m) {
#pragma unroll
        for (int j = 0; j < 4; ++j) {
            const int grow = rowBase + wr * 64 + m * 16 + (lane >> 4) * 4 + j;
            float sv = 0.f, cv = 0.f;
            if (MODE == 0) {
                const int l = grow & (L_SEQ - 1);
                const float ang = (float)(l + 1) * (1.5707963267948966f / (float)L_SEQ);
                __sincosf(ang, &sv, &cv);
            }
#pragma unroll
            for (int n = 0; n < 4; ++n) {
                const int gcol = colBase + wc * 64 + n * 16 + (lane & 15);
                float val = acc[m][n][j] + bias[gcol];
                const size_t oidx = (size_t)grow * E_DIM + gcol;
                if (MODE == 0) {
                    val = fmaxf(val, 0.f);
                    outC[oidx] = f2bf(val * cv);
                    outS[oidx] = f2bf(val * sv);
                } else if (MODE == 1) {
                    outC[oidx] = f2bf(val);
                } else {
                    outF[oidx] = val;
                }
            }
        }
    }
}

// ---------------- kv outer-product partial reduction ----------------
// kv_part[chunk][bh][ {cos:4096, sin:4096} ], sum_part[chunk][bh][ {cos:64, sin:64} ]
__global__ __launch_bounds__(256) void kv_kernel(
    const ushort* __restrict__ Kc, const ushort* __restrict__ Ks, const ushort* __restrict__ V,
    float* __restrict__ kv_part, float* __restrict__ sum_part)
{
    const int chunk = blockIdx.x;   // 0..7
    const int bh = blockIdx.y;      // 0..31
    const int b = bh >> 3, h = bh & 7;
    const int tid = threadIdx.x;
    __shared__ float kcl[16][64];
    __shared__ float ksl[16][64];
    __shared__ float vl[16][64];

    float accC[4][4] = {{0.f}}, accS[4][4] = {{0.f}};
    float sumC[4] = {0.f, 0.f, 0.f, 0.f}, sumS[4] = {0.f, 0.f, 0.f, 0.f};
    const int ki0 = (tid >> 4) * 4;
    const int di0 = (tid & 15) * 4;
    const int sli = tid >> 4;        // 0..15
    const int sc4 = (tid & 15) * 4;  // 0..60

    for (int l0 = chunk * 512; l0 < chunk * 512 + 512; l0 += 16) {
        {
            const size_t base = ((size_t)(b * L_SEQ + l0 + sli)) * E_DIM + h * DHEAD + sc4;
            ushort4 a = *reinterpret_cast<const ushort4*>(&Kc[base]);
            ushort4 s = *reinterpret_cast<const ushort4*>(&Ks[base]);
            ushort4 v = *reinterpret_cast<const ushort4*>(&V[base]);
            *reinterpret_cast<f32x4*>(&kcl[sli][sc4]) = (f32x4){bf2f(a.x), bf2f(a.y), bf2f(a.z), bf2f(a.w)};
            *reinterpret_cast<f32x4*>(&ksl[sli][sc4]) = (f32x4){bf2f(s.x), bf2f(s.y), bf2f(s.z), bf2f(s.w)};
            *reinterpret_cast<f32x4*>(&vl[sli][sc4])  = (f32x4){bf2f(v.x), bf2f(v.y), bf2f(v.z), bf2f(v.w)};
        }
        __syncthreads();
#pragma unroll 4
        for (int t = 0; t < 16; ++t) {
            f32x4 kcv = *reinterpret_cast<const f32x4*>(&kcl[t][ki0]);
            f32x4 ksv = *reinterpret_cast<const f32x4*>(&ksl[t][ki0]);
            f32x4 vv  = *reinterpret_cast<const f32x4*>(&vl[t][di0]);
#pragma unroll
            for (int i = 0; i < 4; ++i) {
#pragma unroll
                for (int j = 0; j < 4; ++j) {
                    accC[i][j] += kcv[i] * vv[j];
                    accS[i][j] += ksv[i] * vv[j];
                }
                sumC[i] += kcv[i];
                sumS[i] += ksv[i];
            }
        }
        __syncthreads();
    }

    const size_t pbase = ((size_t)(chunk * 32 + bh)) * 8192;
#pragma unroll
    for (int i = 0; i < 4; ++i) {
        *reinterpret_cast<f32x4*>(&kv_part[pbase + (size_t)(ki0 + i) * 64 + di0]) =
            (f32x4){accC[i][0], accC[i][1], accC[i][2], accC[i][3]};
        *reinterpret_cast<f32x4*>(&kv_part[pbase + 4096 + (size_t)(ki0 + i) * 64 + di0]) =
            (f32x4){accS[i][0], accS[i][1], accS[i][2], accS[i][3]};
    }
    if ((tid & 15) == 0) {
        const size_t sbase = (size_t)(chunk * 32 + bh) * 128;
#pragma unroll
        for (int i = 0; i < 4; ++i) {
            sum_part[sbase + ki0 + i] = sumC[i];
            sum_part[sbase + 64 + ki0 + i] = sumS[i];
        }
    }
}

// ---------------- reduce partials across 8 chunks ----------------
__global__ __launch_bounds__(256) void kv_reduce_kernel(
    const float* __restrict__ kv_part, const float* __restrict__ sum_part,
    float* __restrict__ kv, float* __restrict__ sums)
{
    const int bh = blockIdx.x;
    const int tid = threadIdx.x;
    for (int idx = tid; idx < 8192; idx += 256) {
        float s = 0.f;
#pragma unroll
        for (int c = 0; c < 8; ++c)
            s += kv_part[((size_t)(c * 32 + bh)) * 8192 + idx];
        kv[(size_t)bh * 8192 + idx] = s;
    }
    if (tid < 128) {
        float s = 0.f;
#pragma unroll
        for (int c = 0; c < 8; ++c)
            s += sum_part[(size_t)(c * 32 + bh) * 128 + tid];
        sums[bh * 128 + tid] = s;
    }
}

// ---------------- attention: per-l matvec against kv + normalization ----------------
__global__ __launch_bounds__(256) void attn_kernel(
    const ushort* __restrict__ Qc, const ushort* __restrict__ Qs,
    const float* __restrict__ kv, const float* __restrict__ sums,
    ushort* __restrict__ attn_out)
{
    const int bh = blockIdx.y;
    const int b = bh >> 3, h = bh & 7;
    const int tid = threadIdx.x;
    __shared__ float kvc[64][64];
    __shared__ float kvs[64][64];
    __shared__ float kcs[64];
    __shared__ float kss[64];

    const float* kvbase = kv + (size_t)bh * 8192;
    for (int i = tid; i < 4096; i += 256) {
        (&kvc[0][0])[i] = kvbase[i];
        (&kvs[0][0])[i] = kvbase[4096 + i];
    }
    if (tid < 64) {
        kcs[tid] = sums[bh * 128 + tid];
        kss[tid] = sums[bh * 128 + 64 + tid];
    }
    __syncthreads();

    const int l = blockIdx.x * 256 + tid;
    const size_t qbase = ((size_t)(b * L_SEQ + l)) * E_DIM + h * DHEAD;

    unsigned int qcp[32], qsp[32];
#pragma unroll
    for (int i = 0; i < 8; ++i) {
        uint4 t0 = reinterpret_cast<const uint4*>(&Qc[qbase])[i];
        qcp[i * 4 + 0] = t0.x; qcp[i * 4 + 1] = t0.y; qcp[i * 4 + 2] = t0.z; qcp[i * 4 + 3] = t0.w;
        uint4 t1 = reinterpret_cast<const uint4*>(&Qs[qbase])[i];
        qsp[i * 4 + 0] = t1.x; qsp[i * 4 + 1] = t1.y; qsp[i * 4 + 2] = t1.z; qsp[i * 4 + 3] = t1.w;
    }

    float att[64];
#pragma unroll
    for (int d = 0; d < 64; ++d) att[d] = 0.f;
    float den = 0.f;

#pragma unroll
    for (int p = 0; p < 32; ++p) {
        const unsigned int wc_ = qcp[p];
        const unsigned int ws_ = qsp[p];
        const float qc0 = bf2f((ushort)(wc_ & 0xffffu));
        const float qc1 = bf2f((ushort)(wc_ >> 16));
        const float qs0 = bf2f((ushort)(ws_ & 0xffffu));
        const float qs1 = bf2f((ushort)(ws_ >> 16));
        const int ki = p * 2;
        den += qc0 * kcs[ki] + qs0 * kss[ki] + qc1 * kcs[ki + 1] + qs1 * kss[ki + 1];
        const f32x4* rc0 = reinterpret_cast<const f32x4*>(&kvc[ki][0]);
        const f32x4* rs0 = reinterpret_cast<const f32x4*>(&kvs[ki][0]);
        const f32x4* rc1 = reinterpret_cast<const f32x4*>(&kvc[ki + 1][0]);
        const f32x4* rs1 = reinterpret_cast<const f32x4*>(&kvs[ki + 1][0]);
#pragma unroll
        for (int d4 = 0; d4 < 16; ++d4) {
            f32x4 c0 = rc0[d4], s0 = rs0[d4], c1 = rc1[d4], s1 = rs1[d4];
#pragma unroll
            for (int e = 0; e < 4; ++e)
                att[d4 * 4 + e] += qc0 * c0[e] + qs0 * s0[e] + qc1 * c1[e] + qs1 * s1[e];
        }
    }

    const float z = 1.f / fmaxf(den, 1e-6f);

    ushort outv[64];
#pragma unroll
    for (int d = 0; d < 64; ++d) outv[d] = f2bf(att[d] * z);
#pragma unroll
    for (int i = 0; i < 8; ++i) {
        uint4 o;
        o.x = (unsigned int)outv[i * 8 + 0] | ((unsigned int)outv[i * 8 + 1] << 16);
        o.y = (unsigned int)outv[i * 8 + 2] | ((unsigned int)outv[i * 8 + 3] << 16);
        o.z = (unsigned int)outv[i * 8 + 4] | ((unsigned int)outv[i * 8 + 5] << 16);
        o.w = (unsigned int)outv[i * 8 + 6] | ((unsigned int)outv[i * 8 + 7] << 16);
        reinterpret_cast<uint4*>(&attn_out[qbase])[i] = o;
    }
}

// ---------------- launch ----------------
extern "C" void kernel_launch(void* const* d_in, const int* in_sizes, int n_in,
                              void* d_out, int out_size, void* d_ws, size_t ws_size,
                              hipStream_t stream) {
    const float* x  = (const float*)d_in[0];
    const float* Wq = (const float*)d_in[1];
    const float* bq = (const float*)d_in[2];
    const float* Wk = (const float*)d_in[3];
    const float* bk = (const float*)d_in[4];
    const float* Wv = (const float*)d_in[5];
    const float* bv = (const float*)d_in[6];
    const float* Wo = (const float*)d_in[7];
    const float* bo = (const float*)d_in[8];
    float* out = (float*)d_out;

    char* ws = (char*)d_ws;
    size_t off = 0;
    auto alloc = [&](size_t bytes) -> char* {
        char* p = ws + off;
        off += (bytes + 255) & ~(size_t)255;
        return p;
    };

    const size_t big = (size_t)NROWS * E_DIM * sizeof(ushort);   // 16.8 MB
    ushort* xb  = (ushort*)alloc(big);
    ushort* wqb = (ushort*)alloc(512 * 512 * sizeof(ushort));
    ushort* wkb = (ushort*)alloc(512 * 512 * sizeof(ushort));
    ushort* wvb = (ushort*)alloc(512 * 512 * sizeof(ushort));
    ushort* wob = (ushort*)alloc(512 * 512 * sizeof(ushort));
    ushort* qc  = (ushort*)alloc(big);
    ushort* qs  = (ushort*)alloc(big);
    ushort* kc  = (ushort*)alloc(big);
    ushort* ks  = (ushort*)alloc(big);
    ushort* vb  = (ushort*)alloc(big);
    // small fp32 buffers for kv reduction (own region; ~9.3 MB)
    float* kv_part  = (float*)alloc((size_t)8 * 32 * 8192 * sizeof(float));
    float* sum_part = (float*)alloc((size_t)8 * 32 * 128 * sizeof(float));
    float* kvbuf    = (float*)alloc((size_t)32 * 8192 * sizeof(float));
    float* sumsbuf  = (float*)alloc((size_t)32 * 128 * sizeof(float));
    // attn output reuses vb's slot? keep separate for clarity; alias vb after kv_kernel.
    ushort* attnb = vb;  // vb is consumed by kv_kernel; attn_kernel runs after (stream-ordered)

    convert_kernel<<<2048, 256, 0, stream>>>(x,  xb,  NROWS * E_DIM / 4);
    convert_kernel<<<256, 256, 0, stream>>>(Wq, wqb, 512 * 512 / 4);
    convert_kernel<<<256, 256, 0, stream>>>(Wk, wkb, 512 * 512 / 4);
    convert_kernel<<<256, 256, 0, stream>>>(Wv, wvb, 512 * 512 / 4);
    convert_kernel<<<256, 256, 0, stream>>>(Wo, wob, 512 * 512 / 4);

    gemm_kernel<0><<<dim3(128, 4), 256, 0, stream>>>(xb, wqb, bq, qc, qs, nullptr);
    gemm_kernel<0><<<dim3(128, 4), 256, 0, stream>>>(xb, wkb, bk, kc, ks, nullptr);
    gemm_kernel<1><<<dim3(128, 4), 256, 0, stream>>>(xb, wvb, bv, vb, nullptr, nullptr);

    kv_kernel<<<dim3(8, 32), 256, 0, stream>>>(kc, ks, vb, kv_part, sum_part);
    kv_reduce_kernel<<<32, 256, 0, stream>>>(kv_part, sum_part, kvbuf, sumsbuf);

    attn_kernel<<<dim3(16, 32), 256, 0, stream>>>(qc, qs, kvbuf, sumsbuf, attnb);

    gemm_kernel<2><<<dim3(128, 4), 256, 0, stream>>>(attnb, wob, bo, nullptr, nullptr, out);
}

// Round 3
// 167.564 us; speedup vs baseline: 2.6985x; 2.6985x over previous
//
#include <hip/hip_runtime.h>
#include <hip/hip_bf16.h>

#define L_SEQ 4096
#define E_DIM 512
#define NHEAD 8
#define DHEAD 64
#define NBATCH 4
#define NROWS (NBATCH * L_SEQ)   // 16384

typedef short bf16x8 __attribute__((ext_vector_type(8)));
typedef float f32x4 __attribute__((ext_vector_type(4)));

__device__ __forceinline__ float bf2f(ushort u) {
    union { float f; unsigned int i; } x;
    x.i = ((unsigned int)u) << 16;
    return x.f;
}
__device__ __forceinline__ ushort f2bf(float f) {
    unsigned int u = __float_as_uint(f);
    unsigned int r = 0x7fffu + ((u >> 16) & 1u);
    u += r;
    return (ushort)(u >> 16);
}

#define GLD16(gptr, lptr) \
    __builtin_amdgcn_global_load_lds( \
        (const __attribute__((address_space(1))) void*)(gptr), \
        (__attribute__((address_space(3))) void*)(lptr), 16, 0, 0)

// ---------------- fp32 -> bf16 conversion ----------------
__global__ void convert_kernel(const float* __restrict__ in, ushort* __restrict__ out, int n4) {
    int stride = gridDim.x * blockDim.x;
    for (int i = blockIdx.x * blockDim.x + threadIdx.x; i < n4; i += stride) {
        float4 f = reinterpret_cast<const float4*>(in)[i];
        ushort4 o;
        o.x = f2bf(f.x); o.y = f2bf(f.y); o.z = f2bf(f.z); o.w = f2bf(f.w);
        reinterpret_cast<ushort4*>(out)[i] = o;
    }
}

// ---------------- MFMA GEMM: out = A(16384x512) @ W^T(512x512) + bias ----------------
// MODE 0: relu, then write val*cos -> outC (bf16) and val*sin -> outS (bf16)
// MODE 1: write val -> outC (bf16)
// MODE 2: write val -> outF (fp32)
template<int MODE>
__global__ __launch_bounds__(256) void gemm_kernel(
    const ushort* __restrict__ A,
    const ushort* __restrict__ W,
    const float* __restrict__ bias,
    ushort* __restrict__ outC,
    ushort* __restrict__ outS,
    float* __restrict__ outF)
{
    __shared__ ushort As[128][32];
    __shared__ ushort Bs[128][32];
    const int tid = threadIdx.x;
    const int lane = tid & 63;
    const int wid = tid >> 6;
    const int wr = wid >> 1, wc = wid & 1;
    const int rowBase = blockIdx.x * 128;
    const int colBase = blockIdx.y * 128;

    f32x4 acc[4][4];
#pragma unroll
    for (int m = 0; m < 4; ++m)
#pragma unroll
        for (int n = 0; n < 4; ++n)
            acc[m][n] = (f32x4){0.f, 0.f, 0.f, 0.f};

    const int lr = tid >> 2;          // 0..63
    const int lc = (tid & 3) * 8;     // 0,8,16,24
    const int frow = lane & 15;
    const int fk = (lane >> 4) * 8;

    for (int k0 = 0; k0 < E_DIM; k0 += 32) {
        GLD16(&A[(size_t)(rowBase + lr) * E_DIM + k0 + lc],      &As[lr][lc]);
        GLD16(&A[(size_t)(rowBase + lr + 64) * E_DIM + k0 + lc], &As[lr + 64][lc]);
        GLD16(&W[(size_t)(colBase + lr) * E_DIM + k0 + lc],      &Bs[lr][lc]);
        GLD16(&W[(size_t)(colBase + lr + 64) * E_DIM + k0 + lc], &Bs[lr + 64][lc]);
        __syncthreads();
        bf16x8 af[4], bfr[4];
#pragma unroll
        for (int m = 0; m < 4; ++m)
            af[m] = *reinterpret_cast<const bf16x8*>(&As[wr * 64 + m * 16 + frow][fk]);
#pragma unroll
        for (int n = 0; n < 4; ++n)
            bfr[n] = *reinterpret_cast<const bf16x8*>(&Bs[wc * 64 + n * 16 + frow][fk]);
#pragma unroll
        for (int m = 0; m < 4; ++m)
#pragma unroll
            for (int n = 0; n < 4; ++n)
                acc[m][n] = __builtin_amdgcn_mfma_f32_16x16x32_bf16(af[m], bfr[n], acc[m][n], 0, 0, 0);
        __syncthreads();
    }

#pragma unroll
    for (int m = 0; m < 4; ++m) {
#pragma unroll
        for (int j = 0; j < 4; ++j) {
            const int grow = rowBase + wr * 64 + m * 16 + (lane >> 4) * 4 + j;
            float sv = 0.f, cv = 0.f;
            if (MODE == 0) {
                const int l = grow & (L_SEQ - 1);
                const float ang = (float)(l + 1) * (1.5707963267948966f / (float)L_SEQ);
                __sincosf(ang, &sv, &cv);
            }
#pragma unroll
            for (int n = 0; n < 4; ++n) {
                const int gcol = colBase + wc * 64 + n * 16 + (lane & 15);
                float val = acc[m][n][j] + bias[gcol];
                const size_t oidx = (size_t)grow * E_DIM + gcol;
                if (MODE == 0) {
                    val = fmaxf(val, 0.f);
                    outC[oidx] = f2bf(val * cv);
                    outS[oidx] = f2bf(val * sv);
                } else if (MODE == 1) {
                    outC[oidx] = f2bf(val);
                } else {
                    outF[oidx] = val;
                }
            }
        }
    }
}

// ---------------- kv outer-product partial reduction ----------------
// kv_part[chunk][bh][ {cos:4096, sin:4096} ], sum_part[chunk][bh][ {cos:64, sin:64} ]
__global__ __launch_bounds__(256) void kv_kernel(
    const ushort* __restrict__ Kc, const ushort* __restrict__ Ks, const ushort* __restrict__ V,
    float* __restrict__ kv_part, float* __restrict__ sum_part)
{
    const int chunk = blockIdx.x;   // 0..7
    const int bh = blockIdx.y;      // 0..31
    const int b = bh >> 3, h = bh & 7;
    const int tid = threadIdx.x;
    __shared__ float kcl[16][64];
    __shared__ float ksl[16][64];
    __shared__ float vl[16][64];

    float accC[4][4] = {{0.f}}, accS[4][4] = {{0.f}};
    float sumC[4] = {0.f, 0.f, 0.f, 0.f}, sumS[4] = {0.f, 0.f, 0.f, 0.f};
    const int ki0 = (tid >> 4) * 4;
    const int di0 = (tid & 15) * 4;
    const int sli = tid >> 4;        // 0..15
    const int sc4 = (tid & 15) * 4;  // 0..60

    for (int l0 = chunk * 512; l0 < chunk * 512 + 512; l0 += 16) {
        {
            const size_t base = ((size_t)(b * L_SEQ + l0 + sli)) * E_DIM + h * DHEAD + sc4;
            ushort4 a = *reinterpret_cast<const ushort4*>(&Kc[base]);
            ushort4 s = *reinterpret_cast<const ushort4*>(&Ks[base]);
            ushort4 v = *reinterpret_cast<const ushort4*>(&V[base]);
            *reinterpret_cast<f32x4*>(&kcl[sli][sc4]) = (f32x4){bf2f(a.x), bf2f(a.y), bf2f(a.z), bf2f(a.w)};
            *reinterpret_cast<f32x4*>(&ksl[sli][sc4]) = (f32x4){bf2f(s.x), bf2f(s.y), bf2f(s.z), bf2f(s.w)};
            *reinterpret_cast<f32x4*>(&vl[sli][sc4])  = (f32x4){bf2f(v.x), bf2f(v.y), bf2f(v.z), bf2f(v.w)};
        }
        __syncthreads();
#pragma unroll 4
        for (int t = 0; t < 16; ++t) {
            f32x4 kcv = *reinterpret_cast<const f32x4*>(&kcl[t][ki0]);
            f32x4 ksv = *reinterpret_cast<const f32x4*>(&ksl[t][ki0]);
            f32x4 vv  = *reinterpret_cast<const f32x4*>(&vl[t][di0]);
#pragma unroll
            for (int i = 0; i < 4; ++i) {
#pragma unroll
                for (int j = 0; j < 4; ++j) {
                    accC[i][j] += kcv[i] * vv[j];
                    accS[i][j] += ksv[i] * vv[j];
                }
                sumC[i] += kcv[i];
                sumS[i] += ksv[i];
            }
        }
        __syncthreads();
    }

    const size_t pbase = ((size_t)(chunk * 32 + bh)) * 8192;
#pragma unroll
    for (int i = 0; i < 4; ++i) {
        *reinterpret_cast<f32x4*>(&kv_part[pbase + (size_t)(ki0 + i) * 64 + di0]) =
            (f32x4){accC[i][0], accC[i][1], accC[i][2], accC[i][3]};
        *reinterpret_cast<f32x4*>(&kv_part[pbase + 4096 + (size_t)(ki0 + i) * 64 + di0]) =
            (f32x4){accS[i][0], accS[i][1], accS[i][2], accS[i][3]};
    }
    if ((tid & 15) == 0) {
        const size_t sbase = (size_t)(chunk * 32 + bh) * 128;
#pragma unroll
        for (int i = 0; i < 4; ++i) {
            sum_part[sbase + ki0 + i] = sumC[i];
            sum_part[sbase + 64 + ki0 + i] = sumS[i];
        }
    }
}

// ---------------- reduce partials; emit bf16 kvT_ext[bh][80][128] ----------------
// rows 0..63: kvT[d][kc] (kc = 0..63 cos-k, 64..127 sin-k)
// row 64: k-sums hi (bf16), row 65: k-sums lo residual, rows 66..79: zero
#define KVT_ROWS 80
#define KVT_STRIDE (KVT_ROWS * 128)   // 10240 ushorts per bh
__global__ __launch_bounds__(256) void kv_reduce_kernel(
    const float* __restrict__ kv_part, const float* __restrict__ sum_part,
    ushort* __restrict__ kvT)
{
    const int bh = blockIdx.x;
    const int tid = threadIdx.x;
    ushort* kvb = kvT + (size_t)bh * KVT_STRIDE;
    for (int idx = tid; idx < 8192; idx += 256) {
        float s = 0.f;
#pragma unroll
        for (int c = 0; c < 8; ++c)
            s += kv_part[((size_t)(c * 32 + bh)) * 8192 + idx];
        const int which = idx >> 12;        // 0 cos, 1 sin
        const int k = (idx >> 6) & 63;
        const int d = idx & 63;
        kvb[d * 128 + which * 64 + k] = f2bf(s);
    }
    if (tid < 128) {
        float s = 0.f;
#pragma unroll
        for (int c = 0; c < 8; ++c)
            s += sum_part[(size_t)(c * 32 + bh) * 128 + tid];
        const ushort hi = f2bf(s);
        const float lo = s - bf2f(hi);
        kvb[64 * 128 + tid] = hi;
        kvb[65 * 128 + tid] = f2bf(lo);
    }
    for (int idx = tid; idx < 14 * 128; idx += 256)
        kvb[66 * 128 + idx] = 0;
}

// ---------------- attention via MFMA: num = [qc|qs] @ [kvc;kvs]^T, den as 5th col-tile ----------------
__global__ __launch_bounds__(256) void attn_kernel(
    const ushort* __restrict__ Qc, const ushort* __restrict__ Qs,
    const ushort* __restrict__ kvT,
    ushort* __restrict__ attn_out)
{
    const int bh = blockIdx.y;
    const int b = bh >> 3, h = bh & 7;
    const int tid = threadIdx.x;
    const int lane = tid & 63;
    const int w = tid >> 6;

    __shared__ ushort Bs[KVT_ROWS][136];     // Bs[row][k_comb], +8 pad

    // stage kvT_ext (20KB) into LDS: 1280 chunks of 8 ushorts; row = 16 chunks
#pragma unroll
    for (int i = 0; i < 5; ++i) {
        const int c = i * 256 + tid;
        const int d = c >> 4, cc = c & 15;
        *reinterpret_cast<uint4*>(&Bs[d][cc * 8]) =
            *reinterpret_cast<const uint4*>(&kvT[(size_t)bh * KVT_STRIDE + (size_t)c * 8]);
    }
    __syncthreads();

    const int rowBase = blockIdx.x * 256 + w * 64;
    const int fr = lane & 15;
    const int g = lane >> 4;

    f32x4 acc[4][5];
#pragma unroll
    for (int m = 0; m < 4; ++m)
#pragma unroll
        for (int n = 0; n < 5; ++n)
            acc[m][n] = (f32x4){0.f, 0.f, 0.f, 0.f};

#pragma unroll
    for (int ks = 0; ks < 4; ++ks) {
        const ushort* __restrict__ src = (ks < 2) ? Qc : Qs;
        const int kk = (ks & 1) * 32 + g * 8;      // offset within qc or qs head slice
        const int kcomb = ks * 32 + g * 8;         // combined k index 0..127

        bf16x8 af[4];
#pragma unroll
        for (int m = 0; m < 4; ++m) {
            const int r = rowBase + m * 16 + fr;
            af[m] = *reinterpret_cast<const bf16x8*>(
                &src[((size_t)(b * L_SEQ) + r) * E_DIM + h * DHEAD + kk]);
        }

        bf16x8 bfr[5];
#pragma unroll
        for (int n = 0; n < 5; ++n)
            bfr[n] = *reinterpret_cast<const bf16x8*>(&Bs[n * 16 + fr][kcomb]);
#pragma unroll
        for (int m = 0; m < 4; ++m)
#pragma unroll
            for (int n = 0; n < 5; ++n)
                acc[m][n] = __builtin_amdgcn_mfma_f32_16x16x32_bf16(af[m], bfr[n], acc[m][n], 0, 0, 0);
    }

#pragma unroll
    for (int m = 0; m < 4; ++m) {
#pragma unroll
        for (int j = 0; j < 4; ++j) {
            // den[row] = D[row][64] + D[row][65]; col 64 lives at fr=0, col 65 at fr=1 (same g)
            const float den = __shfl(acc[m][4][j], g * 16 + 0) + __shfl(acc[m][4][j], g * 16 + 1);
            const float z = 1.f / fmaxf(den, 1e-6f);
            const int grow = rowBase + m * 16 + g * 4 + j;
            const size_t obase = ((size_t)(b * L_SEQ) + grow) * E_DIM + h * DHEAD;
#pragma unroll
            for (int n = 0; n < 4; ++n)
                attn_out[obase + n * 16 + fr] = f2bf(acc[m][n][j] * z);
        }
    }
}

// ---------------- launch ----------------
extern "C" void kernel_launch(void* const* d_in, const int* in_sizes, int n_in,
                              void* d_out, int out_size, void* d_ws, size_t ws_size,
                              hipStream_t stream) {
    const float* x  = (const float*)d_in[0];
    const float* Wq = (const float*)d_in[1];
    const float* bq = (const float*)d_in[2];
    const float* Wk = (const float*)d_in[3];
    const float* bk = (const float*)d_in[4];
    const float* Wv = (const float*)d_in[5];
    const float* bv = (const float*)d_in[6];
    const float* Wo = (const float*)d_in[7];
    const float* bo = (const float*)d_in[8];
    float* out = (float*)d_out;

    char* ws = (char*)d_ws;
    size_t off = 0;
    auto alloc = [&](size_t bytes) -> char* {
        char* p = ws + off;
        off += (bytes + 255) & ~(size_t)255;
        return p;
    };

    const size_t big = (size_t)NROWS * E_DIM * sizeof(ushort);   // 16.8 MB
    ushort* xb  = (ushort*)alloc(big);
    ushort* wqb = (ushort*)alloc(512 * 512 * sizeof(ushort));
    ushort* wkb = (ushort*)alloc(512 * 512 * sizeof(ushort));
    ushort* wvb = (ushort*)alloc(512 * 512 * sizeof(ushort));
    ushort* wob = (ushort*)alloc(512 * 512 * sizeof(ushort));
    ushort* qc  = (ushort*)alloc(big);
    ushort* qs  = (ushort*)alloc(big);
    ushort* kc  = (ushort*)alloc(big);
    ushort* ks  = (ushort*)alloc(big);
    ushort* vb  = (ushort*)alloc(big);
    float* kv_part  = (float*)alloc((size_t)8 * 32 * 8192 * sizeof(float));
    float* sum_part = (float*)alloc((size_t)8 * 32 * 128 * sizeof(float));
    ushort* kvT     = (ushort*)alloc((size_t)32 * KVT_STRIDE * sizeof(ushort));
    ushort* attnb = vb;  // vb is consumed by kv_kernel before attn_kernel writes (stream-ordered)

    convert_kernel<<<2048, 256, 0, stream>>>(x,  xb,  NROWS * E_DIM / 4);
    convert_kernel<<<256, 256, 0, stream>>>(Wq, wqb, 512 * 512 / 4);
    convert_kernel<<<256, 256, 0, stream>>>(Wk, wkb, 512 * 512 / 4);
    convert_kernel<<<256, 256, 0, stream>>>(Wv, wvb, 512 * 512 / 4);
    convert_kernel<<<256, 256, 0, stream>>>(Wo, wob, 512 * 512 / 4);

    gemm_kernel<0><<<dim3(128, 4), 256, 0, stream>>>(xb, wqb, bq, qc, qs, nullptr);
    gemm_kernel<0><<<dim3(128, 4), 256, 0, stream>>>(xb, wkb, bk, kc, ks, nullptr);
    gemm_kernel<1><<<dim3(128, 4), 256, 0, stream>>>(xb, wvb, bv, vb, nullptr, nullptr);

    kv_kernel<<<dim3(8, 32), 256, 0, stream>>>(kc, ks, vb, kv_part, sum_part);
    kv_reduce_kernel<<<32, 256, 0, stream>>>(kv_part, sum_part, kvT);

    attn_kernel<<<dim3(16, 32), 256, 0, stream>>>(qc, qs, kvT, attnb);

    gemm_kernel<2><<<dim3(128, 4), 256, 0, stream>>>(attnb, wob, bo, nullptr, nullptr, out);
}

// Round 4
// 129.485 us; speedup vs baseline: 3.4921x; 1.2941x over previous
//
#include <hip/hip_runtime.h>
#include <hip/hip_bf16.h>

#define L_SEQ 4096
#define E_DIM 512
#define NHEAD 8
#define DHEAD 64
#define NBATCH 4
#define NROWS (NBATCH * L_SEQ)   // 16384

typedef short bf16x8 __attribute__((ext_vector_type(8)));
typedef float f32x4 __attribute__((ext_vector_type(4)));

__device__ __forceinline__ float bf2f(ushort u) {
    union { float f; unsigned int i; } x;
    x.i = ((unsigned int)u) << 16;
    return x.f;
}
__device__ __forceinline__ ushort f2bf(float f) {
    unsigned int u = __float_as_uint(f);
    unsigned int r = 0x7fffu + ((u >> 16) & 1u);
    u += r;
    return (ushort)(u >> 16);
}

#define GLD16(gptr, lptr) \
    __builtin_amdgcn_global_load_lds( \
        (const __attribute__((address_space(1))) void*)(gptr), \
        (__attribute__((address_space(3))) void*)(lptr), 16, 0, 0)

// ---------------- fp32 -> bf16 conversion ----------------
__global__ void convert_kernel(const float* __restrict__ in, ushort* __restrict__ out, int n4) {
    int stride = gridDim.x * blockDim.x;
    for (int i = blockIdx.x * blockDim.x + threadIdx.x; i < n4; i += stride) {
        float4 f = reinterpret_cast<const float4*>(in)[i];
        ushort4 o;
        o.x = f2bf(f.x); o.y = f2bf(f.y); o.z = f2bf(f.z); o.w = f2bf(f.w);
        reinterpret_cast<ushort4*>(out)[i] = o;
    }
}

// ---------------- MFMA GEMM: A(16384x512) @ W^T(512x512) + bias ----------------
// MODE 0: relu; write val*cos -> outC, val*sin -> outS (bf16, normal [l][feat] layout)  [Q]
// MODE 2: write val -> outF (fp32, normal layout)                                       [final]
// MODE 3: relu; TRANSPOSED: outC[bh][k][l] = val*cos, outS[bh][k][l] = val*sin          [K]
// MODE 4: TRANSPOSED: outC[bh][d][l] = val                                              [V]
template<int MODE>
__global__ __launch_bounds__(256) void gemm_kernel(
    const ushort* __restrict__ A,
    const ushort* __restrict__ W,
    const float* __restrict__ bias,
    ushort* __restrict__ outC,
    ushort* __restrict__ outS,
    float* __restrict__ outF)
{
    constexpr bool TRANS = (MODE == 3) || (MODE == 4);
    __shared__ ushort As[128][32];
    __shared__ ushort Bs[128][32];
    __shared__ ushort TS[TRANS ? 128 * 136 : 4];

    const int tid = threadIdx.x;
    const int lane = tid & 63;
    const int wid = tid >> 6;
    const int wr = wid >> 1, wc = wid & 1;
    const int rowBase = blockIdx.x * 128;
    const int colBase = blockIdx.y * 128;

    f32x4 acc[4][4];
#pragma unroll
    for (int m = 0; m < 4; ++m)
#pragma unroll
        for (int n = 0; n < 4; ++n)
            acc[m][n] = (f32x4){0.f, 0.f, 0.f, 0.f};

    const int lr = tid >> 2;          // 0..63
    const int lc = (tid & 3) * 8;     // 0,8,16,24
    const int frow = lane & 15;
    const int fk = (lane >> 4) * 8;
    const int g = lane >> 4;

    for (int k0 = 0; k0 < E_DIM; k0 += 32) {
        GLD16(&A[(size_t)(rowBase + lr) * E_DIM + k0 + lc],      &As[lr][lc]);
        GLD16(&A[(size_t)(rowBase + lr + 64) * E_DIM + k0 + lc], &As[lr + 64][lc]);
        GLD16(&W[(size_t)(colBase + lr) * E_DIM + k0 + lc],      &Bs[lr][lc]);
        GLD16(&W[(size_t)(colBase + lr + 64) * E_DIM + k0 + lc], &Bs[lr + 64][lc]);
        __syncthreads();
        bf16x8 af[4], bfr[4];
#pragma unroll
        for (int m = 0; m < 4; ++m)
            af[m] = *reinterpret_cast<const bf16x8*>(&As[wr * 64 + m * 16 + frow][fk]);
#pragma unroll
        for (int n = 0; n < 4; ++n)
            bfr[n] = *reinterpret_cast<const bf16x8*>(&Bs[wc * 64 + n * 16 + frow][fk]);
#pragma unroll
        for (int m = 0; m < 4; ++m)
#pragma unroll
            for (int n = 0; n < 4; ++n)
                acc[m][n] = __builtin_amdgcn_mfma_f32_16x16x32_bf16(af[m], bfr[n], acc[m][n], 0, 0, 0);
        __syncthreads();
    }

    if constexpr (!TRANS) {
#pragma unroll
        for (int m = 0; m < 4; ++m) {
#pragma unroll
            for (int j = 0; j < 4; ++j) {
                const int grow = rowBase + wr * 64 + m * 16 + g * 4 + j;
                float sv = 0.f, cv = 0.f;
                if (MODE == 0) {
                    const int l = grow & (L_SEQ - 1);
                    const float ang = (float)(l + 1) * (1.5707963267948966f / (float)L_SEQ);
                    __sincosf(ang, &sv, &cv);
                }
#pragma unroll
                for (int n = 0; n < 4; ++n) {
                    const int gcol = colBase + wc * 64 + n * 16 + (lane & 15);
                    float val = acc[m][n][j] + bias[gcol];
                    const size_t oidx = (size_t)grow * E_DIM + gcol;
                    if (MODE == 0) {
                        val = fmaxf(val, 0.f);
                        outC[oidx] = f2bf(val * cv);
                        outS[oidx] = f2bf(val * sv);
                    } else {
                        outF[oidx] = val;
                    }
                }
            }
        }
    } else {
        // scatter (bias/relu'd) values into LDS transposed: TS[featLocal][lLocal]
#pragma unroll
        for (int m = 0; m < 4; ++m) {
#pragma unroll
            for (int j = 0; j < 4; ++j) {
                const int lr_ = wr * 64 + m * 16 + g * 4 + j;
#pragma unroll
                for (int n = 0; n < 4; ++n) {
                    const int lc_ = wc * 64 + n * 16 + (lane & 15);
                    float val = acc[m][n][j] + bias[colBase + lc_];
                    if (MODE == 3) val = fmaxf(val, 0.f);
                    TS[lc_ * 136 + lr_] = f2bf(val);
                }
            }
        }
        __syncthreads();
        // coalesced transposed write: 2048 chunks of 8 ushorts
        const int b = rowBase >> 12;           // batch
        const int lloc = rowBase & (L_SEQ - 1);
        const float C1 = 1.5707963267948966f / (float)L_SEQ;
#pragma unroll
        for (int i = 0; i < 8; ++i) {
            const int c = i * 256 + tid;
            const int r = c >> 4;              // local feature 0..127
            const int cc = c & 15;             // 16B chunk along l
            const int gfeat = colBase + r;
            const size_t dst = ((size_t)(b * E_DIM + gfeat)) * L_SEQ + lloc + cc * 8;
            uint4 raw = *reinterpret_cast<const uint4*>(&TS[r * 136 + cc * 8]);
            ushort u[8] = {
                (ushort)(raw.x & 0xffffu), (ushort)(raw.x >> 16),
                (ushort)(raw.y & 0xffffu), (ushort)(raw.y >> 16),
                (ushort)(raw.z & 0xffffu), (ushort)(raw.z >> 16),
                (ushort)(raw.w & 0xffffu), (ushort)(raw.w >> 16)};
            if (MODE == 4) {
                *reinterpret_cast<uint4*>(&outC[dst]) = raw;
            } else {
                ushort uc[8], us[8];
#pragma unroll
                for (int e = 0; e < 8; ++e) {
                    const int l = lloc + cc * 8 + e;
                    float sv, cv;
                    __sincosf((float)(l + 1) * C1, &sv, &cv);
                    const float v = bf2f(u[e]);
                    uc[e] = f2bf(v * cv);
                    us[e] = f2bf(v * sv);
                }
                uint4 oc, os;
                oc.x = (uint)uc[0] | ((uint)uc[1] << 16); oc.y = (uint)uc[2] | ((uint)uc[3] << 16);
                oc.z = (uint)uc[4] | ((uint)uc[5] << 16); oc.w = (uint)uc[6] | ((uint)uc[7] << 16);
                os.x = (uint)us[0] | ((uint)us[1] << 16); os.y = (uint)us[2] | ((uint)us[3] << 16);
                os.z = (uint)us[4] | ((uint)us[5] << 16); os.w = (uint)us[6] | ((uint)us[7] << 16);
                *reinterpret_cast<uint4*>(&outC[dst]) = oc;
                *reinterpret_cast<uint4*>(&outS[dst]) = os;
            }
        }
    }
}

// ---------------- kv via MFMA, no LDS, no barriers ----------------
// kv_part[chunk][bh][d=64][kcomb=128] fp32 (kcomb: 0..63 cos, 64..127 sin)
// sum_part[chunk][bh][128] fp32 via ones-row MFMA
__global__ __launch_bounds__(256) void kv_kernel(
    const ushort* __restrict__ kcT, const ushort* __restrict__ ksT, const ushort* __restrict__ vT,
    float* __restrict__ kv_part, float* __restrict__ sum_part)
{
    const int chunk = blockIdx.x;   // 0..7
    const int bh = blockIdx.y;      // 0..31
    const int tid = threadIdx.x;
    const int lane = tid & 63;
    const int w = tid >> 6;         // wave = d-frag row
    const int fr = lane & 15;
    const int g = lane >> 4;

    const size_t tbase = (size_t)bh * 64 * L_SEQ;

    f32x4 acc[8], accS[8];
#pragma unroll
    for (int n = 0; n < 8; ++n) {
        acc[n] = (f32x4){0.f, 0.f, 0.f, 0.f};
        accS[n] = (f32x4){0.f, 0.f, 0.f, 0.f};
    }
    bf16x8 ones;
#pragma unroll
    for (int j = 0; j < 8; ++j) ones[j] = (short)0x3F80;

    const int lchunk = chunk * (L_SEQ / 8);
    for (int l0 = lchunk; l0 < lchunk + (L_SEQ / 8); l0 += 32) {
        const int col = l0 + g * 8;
        bf16x8 af = *reinterpret_cast<const bf16x8*>(&vT[tbase + (size_t)(w * 16 + fr) * L_SEQ + col]);
        bf16x8 bc[4], bs[4];
#pragma unroll
        for (int n = 0; n < 4; ++n) {
            bc[n] = *reinterpret_cast<const bf16x8*>(&kcT[tbase + (size_t)(n * 16 + fr) * L_SEQ + col]);
            bs[n] = *reinterpret_cast<const bf16x8*>(&ksT[tbase + (size_t)(n * 16 + fr) * L_SEQ + col]);
        }
#pragma unroll
        for (int n = 0; n < 4; ++n) {
            acc[n]      = __builtin_amdgcn_mfma_f32_16x16x32_bf16(af, bc[n], acc[n], 0, 0, 0);
            acc[n + 4]  = __builtin_amdgcn_mfma_f32_16x16x32_bf16(af, bs[n], acc[n + 4], 0, 0, 0);
            accS[n]     = __builtin_amdgcn_mfma_f32_16x16x32_bf16(ones, bc[n], accS[n], 0, 0, 0);
            accS[n + 4] = __builtin_amdgcn_mfma_f32_16x16x32_bf16(ones, bs[n], accS[n + 4], 0, 0, 0);
        }
    }

    // D[arow=d][brow=kcomb]: d = w*16 + g*4 + j, kcomb = n*16 + fr
    const size_t pbase = ((size_t)(chunk * 32 + bh)) * 8192;
#pragma unroll
    for (int n = 0; n < 8; ++n)
#pragma unroll
        for (int j = 0; j < 4; ++j)
            kv_part[pbase + (size_t)(w * 16 + g * 4 + j) * 128 + n * 16 + fr] = acc[n][j];
    if (w == 0 && g == 0) {
        const size_t sbase = (size_t)(chunk * 32 + bh) * 128;
#pragma unroll
        for (int n = 0; n < 8; ++n)
            sum_part[sbase + n * 16 + fr] = accS[n][0];
    }
}

// ---------------- reduce partials; emit bf16 kvT_ext[bh][80][128] ----------------
// rows 0..63: kv[d][kcomb]; row 64: k-sums hi; row 65: k-sums lo residual; 66..79: zero
#define KVT_ROWS 80
#define KVT_STRIDE (KVT_ROWS * 128)
__global__ __launch_bounds__(256) void kv_reduce_kernel(
    const float* __restrict__ kv_part, const float* __restrict__ sum_part,
    ushort* __restrict__ kvT)
{
    const int bh = blockIdx.x;
    const int tid = threadIdx.x;
    ushort* kvb = kvT + (size_t)bh * KVT_STRIDE;
    for (int idx = tid; idx < 8192; idx += 256) {
        float s = 0.f;
#pragma unroll
        for (int c = 0; c < 8; ++c)
            s += kv_part[((size_t)(c * 32 + bh)) * 8192 + idx];
        kvb[idx] = f2bf(s);
    }
    if (tid < 128) {
        float s = 0.f;
#pragma unroll
        for (int c = 0; c < 8; ++c)
            s += sum_part[(size_t)(c * 32 + bh) * 128 + tid];
        const ushort hi = f2bf(s);
        const float lo = s - bf2f(hi);
        kvb[64 * 128 + tid] = hi;
        kvb[65 * 128 + tid] = f2bf(lo);
    }
    for (int idx = tid; idx < 14 * 128; idx += 256)
        kvb[66 * 128 + idx] = 0;
}

// ---------------- attention via MFMA: num = [qc|qs] @ kv, den as 5th col-tile ----------------
__global__ __launch_bounds__(256) void attn_kernel(
    const ushort* __restrict__ Qc, const ushort* __restrict__ Qs,
    const ushort* __restrict__ kvT,
    ushort* __restrict__ attn_out)
{
    const int bh = blockIdx.y;
    const int b = bh >> 3, h = bh & 7;
    const int tid = threadIdx.x;
    const int lane = tid & 63;
    const int w = tid >> 6;

    __shared__ ushort Bs[KVT_ROWS][136];

    // stage kvT_ext (20KB): 1280 chunks of 8 ushorts; 16 chunks per row
#pragma unroll
    for (int i = 0; i < 5; ++i) {
        const int c = i * 256 + tid;
        const int d = c >> 4, cc = c & 15;
        *reinterpret_cast<uint4*>(&Bs[d][cc * 8]) =
            *reinterpret_cast<const uint4*>(&kvT[(size_t)bh * KVT_STRIDE + (size_t)c * 8]);
    }
    __syncthreads();

    const int rowBase = blockIdx.x * 256 + w * 64;
    const int fr = lane & 15;
    const int g = lane >> 4;

    f32x4 acc[4][5];
#pragma unroll
    for (int m = 0; m < 4; ++m)
#pragma unroll
        for (int n = 0; n < 5; ++n)
            acc[m][n] = (f32x4){0.f, 0.f, 0.f, 0.f};

#pragma unroll
    for (int ks = 0; ks < 4; ++ks) {
        const ushort* __restrict__ src = (ks < 2) ? Qc : Qs;
        const int kk = (ks & 1) * 32 + g * 8;
        const int kcomb = ks * 32 + g * 8;

        bf16x8 af[4];
#pragma unroll
        for (int m = 0; m < 4; ++m) {
            const int r = rowBase + m * 16 + fr;
            af[m] = *reinterpret_cast<const bf16x8*>(
                &src[((size_t)(b * L_SEQ) + r) * E_DIM + h * DHEAD + kk]);
        }

        bf16x8 bfr[5];
#pragma unroll
        for (int n = 0; n < 5; ++n)
            bfr[n] = *reinterpret_cast<const bf16x8*>(&Bs[n * 16 + fr][kcomb]);
#pragma unroll
        for (int m = 0; m < 4; ++m)
#pragma unroll
            for (int n = 0; n < 5; ++n)
                acc[m][n] = __builtin_amdgcn_mfma_f32_16x16x32_bf16(af[m], bfr[n], acc[m][n], 0, 0, 0);
    }

#pragma unroll
    for (int m = 0; m < 4; ++m) {
#pragma unroll
        for (int j = 0; j < 4; ++j) {
            const float den = __shfl(acc[m][4][j], g * 16 + 0) + __shfl(acc[m][4][j], g * 16 + 1);
            const float z = 1.f / fmaxf(den, 1e-6f);
            const int grow = rowBase + m * 16 + g * 4 + j;
            const size_t obase = ((size_t)(b * L_SEQ) + grow) * E_DIM + h * DHEAD;
#pragma unroll
            for (int n = 0; n < 4; ++n)
                attn_out[obase + n * 16 + fr] = f2bf(acc[m][n][j] * z);
        }
    }
}

// ---------------- launch ----------------
extern "C" void kernel_launch(void* const* d_in, const int* in_sizes, int n_in,
                              void* d_out, int out_size, void* d_ws, size_t ws_size,
                              hipStream_t stream) {
    const float* x  = (const float*)d_in[0];
    const float* Wq = (const float*)d_in[1];
    const float* bq = (const float*)d_in[2];
    const float* Wk = (const float*)d_in[3];
    const float* bk = (const float*)d_in[4];
    const float* Wv = (const float*)d_in[5];
    const float* bv = (const float*)d_in[6];
    const float* Wo = (const float*)d_in[7];
    const float* bo = (const float*)d_in[8];
    float* out = (float*)d_out;

    char* ws = (char*)d_ws;
    size_t off = 0;
    auto alloc = [&](size_t bytes) -> char* {
        char* p = ws + off;
        off += (bytes + 255) & ~(size_t)255;
        return p;
    };

    const size_t big = (size_t)NROWS * E_DIM * sizeof(ushort);   // 16.8 MB
    ushort* xb  = (ushort*)alloc(big);
    ushort* wqb = (ushort*)alloc(512 * 512 * sizeof(ushort));
    ushort* wkb = (ushort*)alloc(512 * 512 * sizeof(ushort));
    ushort* wvb = (ushort*)alloc(512 * 512 * sizeof(ushort));
    ushort* wob = (ushort*)alloc(512 * 512 * sizeof(ushort));
    ushort* qc  = (ushort*)alloc(big);
    ushort* qs  = (ushort*)alloc(big);
    ushort* kcT = (ushort*)alloc(big);   // [bh][k][l]
    ushort* ksT = (ushort*)alloc(big);   // [bh][k][l]
    ushort* vT  = (ushort*)alloc(big);   // [bh][d][l]
    float* kv_part  = (float*)alloc((size_t)8 * 32 * 8192 * sizeof(float));
    float* sum_part = (float*)alloc((size_t)8 * 32 * 128 * sizeof(float));
    ushort* kvT     = (ushort*)alloc((size_t)32 * KVT_STRIDE * sizeof(ushort));
    ushort* attnb = kcT;  // kcT fully consumed by kv_kernel before attn_kernel writes (stream-ordered)

    convert_kernel<<<2048, 256, 0, stream>>>(x,  xb,  NROWS * E_DIM / 4);
    convert_kernel<<<256, 256, 0, stream>>>(Wq, wqb, 512 * 512 / 4);
    convert_kernel<<<256, 256, 0, stream>>>(Wk, wkb, 512 * 512 / 4);
    convert_kernel<<<256, 256, 0, stream>>>(Wv, wvb, 512 * 512 / 4);
    convert_kernel<<<256, 256, 0, stream>>>(Wo, wob, 512 * 512 / 4);

    gemm_kernel<0><<<dim3(128, 4), 256, 0, stream>>>(xb, wqb, bq, qc, qs, nullptr);
    gemm_kernel<3><<<dim3(128, 4), 256, 0, stream>>>(xb, wkb, bk, kcT, ksT, nullptr);
    gemm_kernel<4><<<dim3(128, 4), 256, 0, stream>>>(xb, wvb, bv, vT, nullptr, nullptr);

    kv_kernel<<<dim3(8, 32), 256, 0, stream>>>(kcT, ksT, vT, kv_part, sum_part);
    kv_reduce_kernel<<<32, 256, 0, stream>>>(kv_part, sum_part, kvT);

    attn_kernel<<<dim3(16, 32), 256, 0, stream>>>(qc, qs, kvT, attnb);

    gemm_kernel<2><<<dim3(128, 4), 256, 0, stream>>>(attnb, wob, bo, nullptr, nullptr, out);
}

// Round 5
// 125.350 us; speedup vs baseline: 3.6073x; 1.0330x over previous
//
#include <hip/hip_runtime.h>
#include <hip/hip_bf16.h>

#define L_SEQ 4096
#define E_DIM 512
#define NHEAD 8
#define DHEAD 64
#define NBATCH 4
#define NROWS (NBATCH * L_SEQ)   // 16384

typedef short bf16x8 __attribute__((ext_vector_type(8)));
typedef float f32x4 __attribute__((ext_vector_type(4)));

__device__ __forceinline__ float bf2f(ushort u) {
    union { float f; unsigned int i; } x;
    x.i = ((unsigned int)u) << 16;
    return x.f;
}
__device__ __forceinline__ ushort f2bf(float f) {
    unsigned int u = __float_as_uint(f);
    unsigned int r = 0x7fffu + ((u >> 16) & 1u);
    u += r;
    return (ushort)(u >> 16);
}

#define GLD16(gptr, lptr) \
    __builtin_amdgcn_global_load_lds( \
        (const __attribute__((address_space(1))) void*)(gptr), \
        (__attribute__((address_space(3))) void*)(lptr), 16, 0, 0)

// ---------------- fp32 -> bf16 conversion (x) ----------------
__global__ void convert_kernel(const float* __restrict__ in, ushort* __restrict__ out, int n4) {
    int stride = gridDim.x * blockDim.x;
    for (int i = blockIdx.x * blockDim.x + threadIdx.x; i < n4; i += stride) {
        float4 f = reinterpret_cast<const float4*>(in)[i];
        ushort4 o;
        o.x = f2bf(f.x); o.y = f2bf(f.y); o.z = f2bf(f.z); o.w = f2bf(f.w);
        reinterpret_cast<ushort4*>(out)[i] = o;
    }
}

// ---------------- weights conversion + sin/cos tables, one dispatch ----------------
// y = 0..3: convert weight y (65536 float4 chunks). y = 4 (x<16): fill sin/cos tables.
__global__ __launch_bounds__(256) void convert_w_kernel(
    const float* __restrict__ w0, const float* __restrict__ w1,
    const float* __restrict__ w2, const float* __restrict__ w3,
    ushort* __restrict__ o0, ushort* __restrict__ o1,
    ushort* __restrict__ o2, ushort* __restrict__ o3,
    float* __restrict__ sintab, float* __restrict__ costab)
{
    const int tid = threadIdx.x;
    const int y = blockIdx.y;
    if (y == 4) {
        const int l = blockIdx.x * 256 + tid;
        if (blockIdx.x < 16) {
            const float ang = (float)(l + 1) * (1.5707963267948966f / (float)L_SEQ);
            sintab[l] = sinf(ang);
            costab[l] = cosf(ang);
        }
        return;
    }
    const float* in = (y == 0) ? w0 : (y == 1) ? w1 : (y == 2) ? w2 : w3;
    ushort* out = (y == 0) ? o0 : (y == 1) ? o1 : (y == 2) ? o2 : o3;
    const int i = blockIdx.x * 256 + tid;
    float4 f = reinterpret_cast<const float4*>(in)[i];
    ushort4 o;
    o.x = f2bf(f.x); o.y = f2bf(f.y); o.z = f2bf(f.z); o.w = f2bf(f.w);
    reinterpret_cast<ushort4*>(out)[i] = o;
}

// ---------------- fused QKV GEMM: A(16384x512) @ {Wq,Wk,Wv}^T + bias ----------------
// grid (128, 12): y>>2 = mode (0 Q, 1 K, 2 V), y&3 = col block.
// mode 0: relu; qc[l][e] = v*cos, qs[l][e] = v*sin          (normal layout)
// mode 1: relu; kcT[bh][k][l] = v*cos, ksT[bh][k][l] = v*sin (transposed)
// mode 2: vT[bh][d][l] = v                                   (transposed)
// BK=64: 8 K-steps, 32 MFMA per barrier pair. LDS: As/Bs 32KB overlaid by TS 34KB.
__global__ __launch_bounds__(256) void qkv_kernel(
    const ushort* __restrict__ A,
    const ushort* __restrict__ wq, const ushort* __restrict__ wk, const ushort* __restrict__ wv,
    const float* __restrict__ bq, const float* __restrict__ bk, const float* __restrict__ bv,
    const float* __restrict__ sintab, const float* __restrict__ costab,
    ushort* __restrict__ qc, ushort* __restrict__ qs,
    ushort* __restrict__ kcT, ushort* __restrict__ ksT, ushort* __restrict__ vT)
{
    __shared__ ushort SH[17408];            // As[128][64] | Bs[128][64]; reused as TS[128][136]
    ushort* As = SH;
    ushort* Bs = SH + 8192;

    const int tid = threadIdx.x;
    const int lane = tid & 63;
    const int wid = tid >> 6;
    const int wr = wid >> 1, wc = wid & 1;
    const int mode = blockIdx.y >> 2;
    const int colBase = (blockIdx.y & 3) * 128;
    const int rowBase = blockIdx.x * 128;

    const ushort* __restrict__ W = (mode == 0) ? wq : (mode == 1) ? wk : wv;
    const float* __restrict__ bias = (mode == 0) ? bq : (mode == 1) ? bk : bv;

    f32x4 acc[4][4];
#pragma unroll
    for (int m = 0; m < 4; ++m)
#pragma unroll
        for (int n = 0; n < 4; ++n)
            acc[m][n] = (f32x4){0.f, 0.f, 0.f, 0.f};

    const int fr = lane & 15;
    const int g = lane >> 4;
    const int srow = tid >> 3;          // staging row 0..31 per i-step? (c>>3 with c=i*256+tid)
    const int scol = (tid & 7) * 8;

    for (int k0 = 0; k0 < E_DIM; k0 += 64) {
#pragma unroll
        for (int i = 0; i < 4; ++i) {
            const int row = i * 32 + srow;
            GLD16(&A[(size_t)(rowBase + row) * E_DIM + k0 + scol], &As[row * 64 + scol]);
            GLD16(&W[(size_t)(colBase + row) * E_DIM + k0 + scol], &Bs[row * 64 + scol]);
        }
        __syncthreads();
#pragma unroll
        for (int kk = 0; kk < 2; ++kk) {
            bf16x8 af[4], bfr[4];
#pragma unroll
            for (int m = 0; m < 4; ++m)
                af[m] = *reinterpret_cast<const bf16x8*>(&As[(wr * 64 + m * 16 + fr) * 64 + kk * 32 + g * 8]);
#pragma unroll
            for (int n = 0; n < 4; ++n)
                bfr[n] = *reinterpret_cast<const bf16x8*>(&Bs[(wc * 64 + n * 16 + fr) * 64 + kk * 32 + g * 8]);
#pragma unroll
            for (int m = 0; m < 4; ++m)
#pragma unroll
                for (int n = 0; n < 4; ++n)
                    acc[m][n] = __builtin_amdgcn_mfma_f32_16x16x32_bf16(af[m], bfr[n], acc[m][n], 0, 0, 0);
        }
        __syncthreads();
    }

    if (mode == 0) {
#pragma unroll
        for (int m = 0; m < 4; ++m) {
#pragma unroll
            for (int j = 0; j < 4; ++j) {
                const int grow = rowBase + wr * 64 + m * 16 + g * 4 + j;
                const int l = grow & (L_SEQ - 1);
                const float cv = costab[l], sv = sintab[l];
#pragma unroll
                for (int n = 0; n < 4; ++n) {
                    const int gcol = colBase + wc * 64 + n * 16 + fr;
                    float val = fmaxf(acc[m][n][j] + bias[gcol], 0.f);
                    const size_t oidx = (size_t)grow * E_DIM + gcol;
                    qc[oidx] = f2bf(val * cv);
                    qs[oidx] = f2bf(val * sv);
                }
            }
        }
    } else {
        // scatter into LDS transposed: TS[featLocal][lLocal], stride 136
        ushort* TS = SH;
#pragma unroll
        for (int m = 0; m < 4; ++m) {
#pragma unroll
            for (int j = 0; j < 4; ++j) {
                const int lr_ = wr * 64 + m * 16 + g * 4 + j;
#pragma unroll
                for (int n = 0; n < 4; ++n) {
                    const int lc_ = wc * 64 + n * 16 + fr;
                    float val = acc[m][n][j] + bias[colBase + lc_];
                    if (mode == 1) val = fmaxf(val, 0.f);
                    TS[lc_ * 136 + lr_] = f2bf(val);
                }
            }
        }
        __syncthreads();
        const int b = rowBase >> 12;
        const int lloc = rowBase & (L_SEQ - 1);
#pragma unroll
        for (int i = 0; i < 8; ++i) {
            const int c = i * 256 + tid;
            const int r = c >> 4;              // local feature 0..127
            const int cc = c & 15;             // 16B chunk along l
            const int gfeat = colBase + r;
            const size_t dst = ((size_t)(b * E_DIM + gfeat)) * L_SEQ + lloc + cc * 8;
            uint4 raw = *reinterpret_cast<const uint4*>(&TS[r * 136 + cc * 8]);
            if (mode == 2) {
                *reinterpret_cast<uint4*>(&vT[dst]) = raw;
            } else {
                ushort u[8] = {
                    (ushort)(raw.x & 0xffffu), (ushort)(raw.x >> 16),
                    (ushort)(raw.y & 0xffffu), (ushort)(raw.y >> 16),
                    (ushort)(raw.z & 0xffffu), (ushort)(raw.z >> 16),
                    (ushort)(raw.w & 0xffffu), (ushort)(raw.w >> 16)};
                const int lbase = lloc + cc * 8;
                float4 cv0 = *reinterpret_cast<const float4*>(&costab[lbase]);
                float4 cv1 = *reinterpret_cast<const float4*>(&costab[lbase + 4]);
                float4 sv0 = *reinterpret_cast<const float4*>(&sintab[lbase]);
                float4 sv1 = *reinterpret_cast<const float4*>(&sintab[lbase + 4]);
                const float cvv[8] = {cv0.x, cv0.y, cv0.z, cv0.w, cv1.x, cv1.y, cv1.z, cv1.w};
                const float svv[8] = {sv0.x, sv0.y, sv0.z, sv0.w, sv1.x, sv1.y, sv1.z, sv1.w};
                ushort uc[8], us[8];
#pragma unroll
                for (int e = 0; e < 8; ++e) {
                    const float v = bf2f(u[e]);
                    uc[e] = f2bf(v * cvv[e]);
                    us[e] = f2bf(v * svv[e]);
                }
                uint4 oc, os;
                oc.x = (uint)uc[0] | ((uint)uc[1] << 16); oc.y = (uint)uc[2] | ((uint)uc[3] << 16);
                oc.z = (uint)uc[4] | ((uint)uc[5] << 16); oc.w = (uint)uc[6] | ((uint)uc[7] << 16);
                os.x = (uint)us[0] | ((uint)us[1] << 16); os.y = (uint)us[2] | ((uint)us[3] << 16);
                os.z = (uint)us[4] | ((uint)us[5] << 16); os.w = (uint)us[6] | ((uint)us[7] << 16);
                *reinterpret_cast<uint4*>(&kcT[dst]) = oc;
                *reinterpret_cast<uint4*>(&ksT[dst]) = os;
            }
        }
    }
}

// ---------------- out GEMM: attn(16384x512, bf16) @ Wo^T + bo -> fp32 ----------------
__global__ __launch_bounds__(256) void out_gemm_kernel(
    const ushort* __restrict__ A, const ushort* __restrict__ W,
    const float* __restrict__ bias, float* __restrict__ outF)
{
    __shared__ ushort SH[16384];
    ushort* As = SH;
    ushort* Bs = SH + 8192;
    const int tid = threadIdx.x;
    const int lane = tid & 63;
    const int wid = tid >> 6;
    const int wr = wid >> 1, wc = wid & 1;
    const int rowBase = blockIdx.x * 128;
    const int colBase = blockIdx.y * 128;

    f32x4 acc[4][4];
#pragma unroll
    for (int m = 0; m < 4; ++m)
#pragma unroll
        for (int n = 0; n < 4; ++n)
            acc[m][n] = (f32x4){0.f, 0.f, 0.f, 0.f};

    const int fr = lane & 15;
    const int g = lane >> 4;
    const int srow = tid >> 3;
    const int scol = (tid & 7) * 8;

    for (int k0 = 0; k0 < E_DIM; k0 += 64) {
#pragma unroll
        for (int i = 0; i < 4; ++i) {
            const int row = i * 32 + srow;
            GLD16(&A[(size_t)(rowBase + row) * E_DIM + k0 + scol], &As[row * 64 + scol]);
            GLD16(&W[(size_t)(colBase + row) * E_DIM + k0 + scol], &Bs[row * 64 + scol]);
        }
        __syncthreads();
#pragma unroll
        for (int kk = 0; kk < 2; ++kk) {
            bf16x8 af[4], bfr[4];
#pragma unroll
            for (int m = 0; m < 4; ++m)
                af[m] = *reinterpret_cast<const bf16x8*>(&As[(wr * 64 + m * 16 + fr) * 64 + kk * 32 + g * 8]);
#pragma unroll
            for (int n = 0; n < 4; ++n)
                bfr[n] = *reinterpret_cast<const bf16x8*>(&Bs[(wc * 64 + n * 16 + fr) * 64 + kk * 32 + g * 8]);
#pragma unroll
            for (int m = 0; m < 4; ++m)
#pragma unroll
                for (int n = 0; n < 4; ++n)
                    acc[m][n] = __builtin_amdgcn_mfma_f32_16x16x32_bf16(af[m], bfr[n], acc[m][n], 0, 0, 0);
        }
        __syncthreads();
    }

#pragma unroll
    for (int m = 0; m < 4; ++m) {
#pragma unroll
        for (int j = 0; j < 4; ++j) {
            const int grow = rowBase + wr * 64 + m * 16 + g * 4 + j;
#pragma unroll
            for (int n = 0; n < 4; ++n) {
                const int gcol = colBase + wc * 64 + n * 16 + fr;
                outF[(size_t)grow * E_DIM + gcol] = acc[m][n][j] + bias[gcol];
            }
        }
    }
}

// ---------------- kv via MFMA, no LDS, no barriers ----------------
__global__ __launch_bounds__(256) void kv_kernel(
    const ushort* __restrict__ kcT, const ushort* __restrict__ ksT, const ushort* __restrict__ vT,
    float* __restrict__ kv_part, float* __restrict__ sum_part)
{
    const int chunk = blockIdx.x;   // 0..7
    const int bh = blockIdx.y;      // 0..31
    const int tid = threadIdx.x;
    const int lane = tid & 63;
    const int w = tid >> 6;
    const int fr = lane & 15;
    const int g = lane >> 4;

    const size_t tbase = (size_t)bh * 64 * L_SEQ;

    f32x4 acc[8], accS[8];
#pragma unroll
    for (int n = 0; n < 8; ++n) {
        acc[n] = (f32x4){0.f, 0.f, 0.f, 0.f};
        accS[n] = (f32x4){0.f, 0.f, 0.f, 0.f};
    }
    bf16x8 ones;
#pragma unroll
    for (int j = 0; j < 8; ++j) ones[j] = (short)0x3F80;

    const int lchunk = chunk * (L_SEQ / 8);
    for (int l0 = lchunk; l0 < lchunk + (L_SEQ / 8); l0 += 32) {
        const int col = l0 + g * 8;
        bf16x8 af = *reinterpret_cast<const bf16x8*>(&vT[tbase + (size_t)(w * 16 + fr) * L_SEQ + col]);
        bf16x8 bc[4], bs[4];
#pragma unroll
        for (int n = 0; n < 4; ++n) {
            bc[n] = *reinterpret_cast<const bf16x8*>(&kcT[tbase + (size_t)(n * 16 + fr) * L_SEQ + col]);
            bs[n] = *reinterpret_cast<const bf16x8*>(&ksT[tbase + (size_t)(n * 16 + fr) * L_SEQ + col]);
        }
#pragma unroll
        for (int n = 0; n < 4; ++n) {
            acc[n]      = __builtin_amdgcn_mfma_f32_16x16x32_bf16(af, bc[n], acc[n], 0, 0, 0);
            acc[n + 4]  = __builtin_amdgcn_mfma_f32_16x16x32_bf16(af, bs[n], acc[n + 4], 0, 0, 0);
            accS[n]     = __builtin_amdgcn_mfma_f32_16x16x32_bf16(ones, bc[n], accS[n], 0, 0, 0);
            accS[n + 4] = __builtin_amdgcn_mfma_f32_16x16x32_bf16(ones, bs[n], accS[n + 4], 0, 0, 0);
        }
    }

    const size_t pbase = ((size_t)(chunk * 32 + bh)) * 8192;
#pragma unroll
    for (int n = 0; n < 8; ++n)
#pragma unroll
        for (int j = 0; j < 4; ++j)
            kv_part[pbase + (size_t)(w * 16 + g * 4 + j) * 128 + n * 16 + fr] = acc[n][j];
    if (w == 0 && g == 0) {
        const size_t sbase = (size_t)(chunk * 32 + bh) * 128;
#pragma unroll
        for (int n = 0; n < 8; ++n)
            sum_part[sbase + n * 16 + fr] = accS[n][0];
    }
}

// ---------------- reduce partials; emit bf16 kvT_ext[bh][80][128] ----------------
#define KVT_ROWS 80
#define KVT_STRIDE (KVT_ROWS * 128)
__global__ __launch_bounds__(256) void kv_reduce_kernel(
    const float* __restrict__ kv_part, const float* __restrict__ sum_part,
    ushort* __restrict__ kvT)
{
    const int bh = blockIdx.x;
    const int tid = threadIdx.x;
    ushort* kvb = kvT + (size_t)bh * KVT_STRIDE;
    for (int idx = tid; idx < 8192; idx += 256) {
        float s = 0.f;
#pragma unroll
        for (int c = 0; c < 8; ++c)
            s += kv_part[((size_t)(c * 32 + bh)) * 8192 + idx];
        kvb[idx] = f2bf(s);
    }
    if (tid < 128) {
        float s = 0.f;
#pragma unroll
        for (int c = 0; c < 8; ++c)
            s += sum_part[(size_t)(c * 32 + bh) * 128 + tid];
        const ushort hi = f2bf(s);
        const float lo = s - bf2f(hi);
        kvb[64 * 128 + tid] = hi;
        kvb[65 * 128 + tid] = f2bf(lo);
    }
    for (int idx = tid; idx < 14 * 128; idx += 256)
        kvb[66 * 128 + idx] = 0;
}

// ---------------- attention via MFMA: num = [qc|qs] @ kv, den as 5th col-tile ----------------
__global__ __launch_bounds__(256) void attn_kernel(
    const ushort* __restrict__ Qc, const ushort* __restrict__ Qs,
    const ushort* __restrict__ kvT,
    ushort* __restrict__ attn_out)
{
    const int bh = blockIdx.y;
    const int b = bh >> 3, h = bh & 7;
    const int tid = threadIdx.x;
    const int lane = tid & 63;
    const int w = tid >> 6;

    __shared__ ushort Bs[KVT_ROWS][136];

#pragma unroll
    for (int i = 0; i < 5; ++i) {
        const int c = i * 256 + tid;
        const int d = c >> 4, cc = c & 15;
        *reinterpret_cast<uint4*>(&Bs[d][cc * 8]) =
            *reinterpret_cast<const uint4*>(&kvT[(size_t)bh * KVT_STRIDE + (size_t)c * 8]);
    }
    __syncthreads();

    const int rowBase = blockIdx.x * 256 + w * 64;
    const int fr = lane & 15;
    const int g = lane >> 4;

    f32x4 acc[4][5];
#pragma unroll
    for (int m = 0; m < 4; ++m)
#pragma unroll
        for (int n = 0; n < 5; ++n)
            acc[m][n] = (f32x4){0.f, 0.f, 0.f, 0.f};

#pragma unroll
    for (int ks = 0; ks < 4; ++ks) {
        const ushort* __restrict__ src = (ks < 2) ? Qc : Qs;
        const int kk = (ks & 1) * 32 + g * 8;
        const int kcomb = ks * 32 + g * 8;

        bf16x8 af[4];
#pragma unroll
        for (int m = 0; m < 4; ++m) {
            const int r = rowBase + m * 16 + fr;
            af[m] = *reinterpret_cast<const bf16x8*>(
                &src[((size_t)(b * L_SEQ) + r) * E_DIM + h * DHEAD + kk]);
        }

        bf16x8 bfr[5];
#pragma unroll
        for (int n = 0; n < 5; ++n)
            bfr[n] = *reinterpret_cast<const bf16x8*>(&Bs[n * 16 + fr][kcomb]);
#pragma unroll
        for (int m = 0; m < 4; ++m)
#pragma unroll
            for (int n = 0; n < 5; ++n)
                acc[m][n] = __builtin_amdgcn_mfma_f32_16x16x32_bf16(af[m], bfr[n], acc[m][n], 0, 0, 0);
    }

#pragma unroll
    for (int m = 0; m < 4; ++m) {
#pragma unroll
        for (int j = 0; j < 4; ++j) {
            const float den = __shfl(acc[m][4][j], g * 16 + 0) + __shfl(acc[m][4][j], g * 16 + 1);
            const float z = 1.f / fmaxf(den, 1e-6f);
            const int grow = rowBase + m * 16 + g * 4 + j;
            const size_t obase = ((size_t)(b * L_SEQ) + grow) * E_DIM + h * DHEAD;
#pragma unroll
            for (int n = 0; n < 4; ++n)
                attn_out[obase + n * 16 + fr] = f2bf(acc[m][n][j] * z);
        }
    }
}

// ---------------- launch ----------------
extern "C" void kernel_launch(void* const* d_in, const int* in_sizes, int n_in,
                              void* d_out, int out_size, void* d_ws, size_t ws_size,
                              hipStream_t stream) {
    const float* x  = (const float*)d_in[0];
    const float* Wq = (const float*)d_in[1];
    const float* bq = (const float*)d_in[2];
    const float* Wk = (const float*)d_in[3];
    const float* bk = (const float*)d_in[4];
    const float* Wv = (const float*)d_in[5];
    const float* bv = (const float*)d_in[6];
    const float* Wo = (const float*)d_in[7];
    const float* bo = (const float*)d_in[8];
    float* out = (float*)d_out;

    char* ws = (char*)d_ws;
    size_t off = 0;
    auto alloc = [&](size_t bytes) -> char* {
        char* p = ws + off;
        off += (bytes + 255) & ~(size_t)255;
        return p;
    };

    const size_t big = (size_t)NROWS * E_DIM * sizeof(ushort);   // 16.8 MB
    ushort* xb  = (ushort*)alloc(big);
    ushort* wqb = (ushort*)alloc(512 * 512 * sizeof(ushort));
    ushort* wkb = (ushort*)alloc(512 * 512 * sizeof(ushort));
    ushort* wvb = (ushort*)alloc(512 * 512 * sizeof(ushort));
    ushort* wob = (ushort*)alloc(512 * 512 * sizeof(ushort));
    ushort* qc  = (ushort*)alloc(big);
    ushort* qs  = (ushort*)alloc(big);
    ushort* kcT = (ushort*)alloc(big);   // [bh][k][l]
    ushort* ksT = (ushort*)alloc(big);   // [bh][k][l]
    ushort* vT  = (ushort*)alloc(big);   // [bh][d][l]
    float* kv_part  = (float*)alloc((size_t)8 * 32 * 8192 * sizeof(float));
    float* sum_part = (float*)alloc((size_t)8 * 32 * 128 * sizeof(float));
    ushort* kvT     = (ushort*)alloc((size_t)32 * KVT_STRIDE * sizeof(ushort));
    float* sintab   = (float*)alloc(L_SEQ * sizeof(float));
    float* costab   = (float*)alloc(L_SEQ * sizeof(float));
    ushort* attnb = kcT;  // kcT fully consumed by kv_kernel before attn_kernel writes

    convert_kernel<<<2048, 256, 0, stream>>>(x, xb, NROWS * E_DIM / 4);
    convert_w_kernel<<<dim3(256, 5), 256, 0, stream>>>(
        Wq, Wk, Wv, Wo, wqb, wkb, wvb, wob, sintab, costab);

    qkv_kernel<<<dim3(128, 12), 256, 0, stream>>>(
        xb, wqb, wkb, wvb, bq, bk, bv, sintab, costab, qc, qs, kcT, ksT, vT);

    kv_kernel<<<dim3(8, 32), 256, 0, stream>>>(kcT, ksT, vT, kv_part, sum_part);
    kv_reduce_kernel<<<32, 256, 0, stream>>>(kv_part, sum_part, kvT);

    attn_kernel<<<dim3(16, 32), 256, 0, stream>>>(qc, qs, kvT, attnb);

    out_gemm_kernel<<<dim3(128, 4), 256, 0, stream>>>(attnb, wob, bo, out);
}

// Round 6
// 119.005 us; speedup vs baseline: 3.7996x; 1.0533x over previous
//
#include <hip/hip_runtime.h>
#include <hip/hip_bf16.h>

#define L_SEQ 4096
#define E_DIM 512
#define NHEAD 8
#define DHEAD 64
#define NBATCH 4
#define NROWS (NBATCH * L_SEQ)   // 16384

typedef short bf16x8 __attribute__((ext_vector_type(8)));
typedef float f32x4 __attribute__((ext_vector_type(4)));

__device__ __forceinline__ float bf2f(ushort u) {
    union { float f; unsigned int i; } x;
    x.i = ((unsigned int)u) << 16;
    return x.f;
}
__device__ __forceinline__ ushort f2bf(float f) {
    unsigned int u = __float_as_uint(f);
    unsigned int r = 0x7fffu + ((u >> 16) & 1u);
    u += r;
    return (ushort)(u >> 16);
}

#define GLD16(gptr, lptr) \
    __builtin_amdgcn_global_load_lds( \
        (const __attribute__((address_space(1))) void*)(gptr), \
        (__attribute__((address_space(3))) void*)(lptr), 16, 0, 0)

// ---------------- fp32 -> bf16 conversion (x) ----------------
__global__ void convert_kernel(const float* __restrict__ in, ushort* __restrict__ out, int n4) {
    int stride = gridDim.x * blockDim.x;
    for (int i = blockIdx.x * blockDim.x + threadIdx.x; i < n4; i += stride) {
        float4 f = reinterpret_cast<const float4*>(in)[i];
        ushort4 o;
        o.x = f2bf(f.x); o.y = f2bf(f.y); o.z = f2bf(f.z); o.w = f2bf(f.w);
        reinterpret_cast<ushort4*>(out)[i] = o;
    }
}

// ---------------- weights conversion + sin/cos tables, one dispatch ----------------
__global__ __launch_bounds__(256) void convert_w_kernel(
    const float* __restrict__ w0, const float* __restrict__ w1,
    const float* __restrict__ w2, const float* __restrict__ w3,
    ushort* __restrict__ o0, ushort* __restrict__ o1,
    ushort* __restrict__ o2, ushort* __restrict__ o3,
    float* __restrict__ sintab, float* __restrict__ costab)
{
    const int tid = threadIdx.x;
    const int y = blockIdx.y;
    if (y == 4) {
        const int l = blockIdx.x * 256 + tid;
        if (blockIdx.x < 16) {
            const float ang = (float)(l + 1) * (1.5707963267948966f / (float)L_SEQ);
            sintab[l] = sinf(ang);
            costab[l] = cosf(ang);
        }
        return;
    }
    const float* in = (y == 0) ? w0 : (y == 1) ? w1 : (y == 2) ? w2 : w3;
    ushort* out = (y == 0) ? o0 : (y == 1) ? o1 : (y == 2) ? o2 : o3;
    const int i = blockIdx.x * 256 + tid;
    float4 f = reinterpret_cast<const float4*>(in)[i];
    ushort4 o;
    o.x = f2bf(f.x); o.y = f2bf(f.y); o.z = f2bf(f.z); o.w = f2bf(f.w);
    reinterpret_cast<ushort4*>(out)[i] = o;
}

// ---------------- fused QKV GEMM: A(16384x512) @ {Wq,Wk,Wv}^T + bias ----------------
// grid (128, 12): y>>2 = mode (0 Q, 1 K, 2 V), y&3 = col block.
// LDS tiles are XOR-swizzled (T2, rule #21): linear global_load_lds dest +
// pre-swizzled global source (16B chunk c16 holds tile chunk c16^(row&7)) +
// matching XOR on the ds_read side. 2-way residual conflict only (free).
__global__ __launch_bounds__(256) void qkv_kernel(
    const ushort* __restrict__ A,
    const ushort* __restrict__ wq, const ushort* __restrict__ wk, const ushort* __restrict__ wv,
    const float* __restrict__ bq, const float* __restrict__ bk, const float* __restrict__ bv,
    const float* __restrict__ sintab, const float* __restrict__ costab,
    ushort* __restrict__ qc, ushort* __restrict__ qs,
    ushort* __restrict__ kcT, ushort* __restrict__ ksT, ushort* __restrict__ vT)
{
    __shared__ ushort SH[17408];            // As[128][64] | Bs[128][64]; reused as TS[128][136]
    ushort* As = SH;
    ushort* Bs = SH + 8192;

    const int tid = threadIdx.x;
    const int lane = tid & 63;
    const int wid = tid >> 6;
    const int wr = wid >> 1, wc = wid & 1;
    const int mode = blockIdx.y >> 2;
    const int colBase = (blockIdx.y & 3) * 128;
    const int rowBase = blockIdx.x * 128;

    const ushort* __restrict__ W = (mode == 0) ? wq : (mode == 1) ? wk : wv;
    const float* __restrict__ bias = (mode == 0) ? bq : (mode == 1) ? bk : bv;

    f32x4 acc[4][4];
#pragma unroll
    for (int m = 0; m < 4; ++m)
#pragma unroll
        for (int n = 0; n < 4; ++n)
            acc[m][n] = (f32x4){0.f, 0.f, 0.f, 0.f};

    const int fr = lane & 15;
    const int g = lane >> 4;
    const int fr7 = fr & 7;
    // staging: thread -> (row, c16); source chunk pre-swizzled by row&7
    const int c16s = tid & 7;
    const int rbase_s = tid >> 3;               // 0..31
    const int srcCol = (c16s ^ (rbase_s & 7)) * 8;

    for (int k0 = 0; k0 < E_DIM; k0 += 64) {
#pragma unroll
        for (int i = 0; i < 4; ++i) {
            const int row = i * 32 + rbase_s;
            GLD16(&A[(size_t)(rowBase + row) * E_DIM + k0 + srcCol], &As[row * 64 + c16s * 8]);
            GLD16(&W[(size_t)(colBase + row) * E_DIM + k0 + srcCol], &Bs[row * 64 + c16s * 8]);
        }
        __syncthreads();
#pragma unroll
        for (int kk = 0; kk < 2; ++kk) {
            const int cR = (((kk * 4 + g) ^ fr7)) * 8;    // swizzled 16B chunk for this lane
            bf16x8 af[4], bfr[4];
#pragma unroll
            for (int m = 0; m < 4; ++m)
                af[m] = *reinterpret_cast<const bf16x8*>(&As[(wr * 64 + m * 16 + fr) * 64 + cR]);
#pragma unroll
            for (int n = 0; n < 4; ++n)
                bfr[n] = *reinterpret_cast<const bf16x8*>(&Bs[(wc * 64 + n * 16 + fr) * 64 + cR]);
#pragma unroll
            for (int m = 0; m < 4; ++m)
#pragma unroll
                for (int n = 0; n < 4; ++n)
                    acc[m][n] = __builtin_amdgcn_mfma_f32_16x16x32_bf16(af[m], bfr[n], acc[m][n], 0, 0, 0);
        }
        __syncthreads();
    }

    if (mode == 0) {
#pragma unroll
        for (int m = 0; m < 4; ++m) {
#pragma unroll
            for (int j = 0; j < 4; ++j) {
                const int grow = rowBase + wr * 64 + m * 16 + g * 4 + j;
                const int l = grow & (L_SEQ - 1);
                const float cv = costab[l], sv = sintab[l];
#pragma unroll
                for (int n = 0; n < 4; ++n) {
                    const int gcol = colBase + wc * 64 + n * 16 + fr;
                    float val = fmaxf(acc[m][n][j] + bias[gcol], 0.f);
                    const size_t oidx = (size_t)grow * E_DIM + gcol;
                    qc[oidx] = f2bf(val * cv);
                    qs[oidx] = f2bf(val * sv);
                }
            }
        }
    } else {
        // scatter into LDS transposed: TS[featLocal][lLocal], stride 136
        ushort* TS = SH;
#pragma unroll
        for (int m = 0; m < 4; ++m) {
#pragma unroll
            for (int j = 0; j < 4; ++j) {
                const int lr_ = wr * 64 + m * 16 + g * 4 + j;
#pragma unroll
                for (int n = 0; n < 4; ++n) {
                    const int lc_ = wc * 64 + n * 16 + fr;
                    float val = acc[m][n][j] + bias[colBase + lc_];
                    if (mode == 1) val = fmaxf(val, 0.f);
                    TS[lc_ * 136 + lr_] = f2bf(val);
                }
            }
        }
        __syncthreads();
        const int b = rowBase >> 12;
        const int lloc = rowBase & (L_SEQ - 1);
#pragma unroll
        for (int i = 0; i < 8; ++i) {
            const int c = i * 256 + tid;
            const int r = c >> 4;              // local feature 0..127
            const int cc = c & 15;             // 16B chunk along l
            const int gfeat = colBase + r;
            const size_t dst = ((size_t)(b * E_DIM + gfeat)) * L_SEQ + lloc + cc * 8;
            uint4 raw = *reinterpret_cast<const uint4*>(&TS[r * 136 + cc * 8]);
            if (mode == 2) {
                *reinterpret_cast<uint4*>(&vT[dst]) = raw;
            } else {
                ushort u[8] = {
                    (ushort)(raw.x & 0xffffu), (ushort)(raw.x >> 16),
                    (ushort)(raw.y & 0xffffu), (ushort)(raw.y >> 16),
                    (ushort)(raw.z & 0xffffu), (ushort)(raw.z >> 16),
                    (ushort)(raw.w & 0xffffu), (ushort)(raw.w >> 16)};
                const int lbase = lloc + cc * 8;
                float4 cv0 = *reinterpret_cast<const float4*>(&costab[lbase]);
                float4 cv1 = *reinterpret_cast<const float4*>(&costab[lbase + 4]);
                float4 sv0 = *reinterpret_cast<const float4*>(&sintab[lbase]);
                float4 sv1 = *reinterpret_cast<const float4*>(&sintab[lbase + 4]);
                const float cvv[8] = {cv0.x, cv0.y, cv0.z, cv0.w, cv1.x, cv1.y, cv1.z, cv1.w};
                const float svv[8] = {sv0.x, sv0.y, sv0.z, sv0.w, sv1.x, sv1.y, sv1.z, sv1.w};
                ushort uc[8], us[8];
#pragma unroll
                for (int e = 0; e < 8; ++e) {
                    const float v = bf2f(u[e]);
                    uc[e] = f2bf(v * cvv[e]);
                    us[e] = f2bf(v * svv[e]);
                }
                uint4 oc, os;
                oc.x = (uint)uc[0] | ((uint)uc[1] << 16); oc.y = (uint)uc[2] | ((uint)uc[3] << 16);
                oc.z = (uint)uc[4] | ((uint)uc[5] << 16); oc.w = (uint)uc[6] | ((uint)uc[7] << 16);
                os.x = (uint)us[0] | ((uint)us[1] << 16); os.y = (uint)us[2] | ((uint)us[3] << 16);
                os.z = (uint)us[4] | ((uint)us[5] << 16); os.w = (uint)us[6] | ((uint)us[7] << 16);
                *reinterpret_cast<uint4*>(&kcT[dst]) = oc;
                *reinterpret_cast<uint4*>(&ksT[dst]) = os;
            }
        }
    }
}

// ---------------- out GEMM: attn(16384x512, bf16) @ Wo^T + bo -> fp32 ----------------
__global__ __launch_bounds__(256) void out_gemm_kernel(
    const ushort* __restrict__ A, const ushort* __restrict__ W,
    const float* __restrict__ bias, float* __restrict__ outF)
{
    __shared__ ushort SH[16384];
    ushort* As = SH;
    ushort* Bs = SH + 8192;
    const int tid = threadIdx.x;
    const int lane = tid & 63;
    const int wid = tid >> 6;
    const int wr = wid >> 1, wc = wid & 1;
    const int rowBase = blockIdx.x * 128;
    const int colBase = blockIdx.y * 128;

    f32x4 acc[4][4];
#pragma unroll
    for (int m = 0; m < 4; ++m)
#pragma unroll
        for (int n = 0; n < 4; ++n)
            acc[m][n] = (f32x4){0.f, 0.f, 0.f, 0.f};

    const int fr = lane & 15;
    const int g = lane >> 4;
    const int fr7 = fr & 7;
    const int c16s = tid & 7;
    const int rbase_s = tid >> 3;
    const int srcCol = (c16s ^ (rbase_s & 7)) * 8;

    for (int k0 = 0; k0 < E_DIM; k0 += 64) {
#pragma unroll
        for (int i = 0; i < 4; ++i) {
            const int row = i * 32 + rbase_s;
            GLD16(&A[(size_t)(rowBase + row) * E_DIM + k0 + srcCol], &As[row * 64 + c16s * 8]);
            GLD16(&W[(size_t)(colBase + row) * E_DIM + k0 + srcCol], &Bs[row * 64 + c16s * 8]);
        }
        __syncthreads();
#pragma unroll
        for (int kk = 0; kk < 2; ++kk) {
            const int cR = (((kk * 4 + g) ^ fr7)) * 8;
            bf16x8 af[4], bfr[4];
#pragma unroll
            for (int m = 0; m < 4; ++m)
                af[m] = *reinterpret_cast<const bf16x8*>(&As[(wr * 64 + m * 16 + fr) * 64 + cR]);
#pragma unroll
            for (int n = 0; n < 4; ++n)
                bfr[n] = *reinterpret_cast<const bf16x8*>(&Bs[(wc * 64 + n * 16 + fr) * 64 + cR]);
#pragma unroll
            for (int m = 0; m < 4; ++m)
#pragma unroll
                for (int n = 0; n < 4; ++n)
                    acc[m][n] = __builtin_amdgcn_mfma_f32_16x16x32_bf16(af[m], bfr[n], acc[m][n], 0, 0, 0);
        }
        __syncthreads();
    }

#pragma unroll
    for (int m = 0; m < 4; ++m) {
#pragma unroll
        for (int j = 0; j < 4; ++j) {
            const int grow = rowBase + wr * 64 + m * 16 + g * 4 + j;
#pragma unroll
            for (int n = 0; n < 4; ++n) {
                const int gcol = colBase + wc * 64 + n * 16 + fr;
                outF[(size_t)grow * E_DIM + gcol] = acc[m][n][j] + bias[gcol];
            }
        }
    }
}

// ---------------- kv via MFMA, no LDS, no barriers ----------------
__global__ __launch_bounds__(256) void kv_kernel(
    const ushort* __restrict__ kcT, const ushort* __restrict__ ksT, const ushort* __restrict__ vT,
    float* __restrict__ kv_part, float* __restrict__ sum_part)
{
    const int chunk = blockIdx.x;   // 0..7
    const int bh = blockIdx.y;      // 0..31
    const int tid = threadIdx.x;
    const int lane = tid & 63;
    const int w = tid >> 6;
    const int fr = lane & 15;
    const int g = lane >> 4;

    const size_t tbase = (size_t)bh * 64 * L_SEQ;

    f32x4 acc[8], accS[8];
#pragma unroll
    for (int n = 0; n < 8; ++n) {
        acc[n] = (f32x4){0.f, 0.f, 0.f, 0.f};
        accS[n] = (f32x4){0.f, 0.f, 0.f, 0.f};
    }
    bf16x8 ones;
#pragma unroll
    for (int j = 0; j < 8; ++j) ones[j] = (short)0x3F80;

    const int lchunk = chunk * (L_SEQ / 8);
    for (int l0 = lchunk; l0 < lchunk + (L_SEQ / 8); l0 += 32) {
        const int col = l0 + g * 8;
        bf16x8 af = *reinterpret_cast<const bf16x8*>(&vT[tbase + (size_t)(w * 16 + fr) * L_SEQ + col]);
        bf16x8 bc[4], bs[4];
#pragma unroll
        for (int n = 0; n < 4; ++n) {
            bc[n] = *reinterpret_cast<const bf16x8*>(&kcT[tbase + (size_t)(n * 16 + fr) * L_SEQ + col]);
            bs[n] = *reinterpret_cast<const bf16x8*>(&ksT[tbase + (size_t)(n * 16 + fr) * L_SEQ + col]);
        }
#pragma unroll
        for (int n = 0; n < 4; ++n) {
            acc[n]      = __builtin_amdgcn_mfma_f32_16x16x32_bf16(af, bc[n], acc[n], 0, 0, 0);
            acc[n + 4]  = __builtin_amdgcn_mfma_f32_16x16x32_bf16(af, bs[n], acc[n + 4], 0, 0, 0);
            accS[n]     = __builtin_amdgcn_mfma_f32_16x16x32_bf16(ones, bc[n], accS[n], 0, 0, 0);
            accS[n + 4] = __builtin_amdgcn_mfma_f32_16x16x32_bf16(ones, bs[n], accS[n + 4], 0, 0, 0);
        }
    }

    const size_t pbase = ((size_t)(chunk * 32 + bh)) * 8192;
#pragma unroll
    for (int n = 0; n < 8; ++n)
#pragma unroll
        for (int j = 0; j < 4; ++j)
            kv_part[pbase + (size_t)(w * 16 + g * 4 + j) * 128 + n * 16 + fr] = acc[n][j];
    if (w == 0 && g == 0) {
        const size_t sbase = (size_t)(chunk * 32 + bh) * 128;
#pragma unroll
        for (int n = 0; n < 8; ++n)
            sum_part[sbase + n * 16 + fr] = accS[n][0];
    }
}

// ---------------- reduce partials; emit bf16 kvT_ext[bh][80][128] ----------------
#define KVT_ROWS 80
#define KVT_STRIDE (KVT_ROWS * 128)
__global__ __launch_bounds__(256) void kv_reduce_kernel(
    const float* __restrict__ kv_part, const float* __restrict__ sum_part,
    ushort* __restrict__ kvT)
{
    const int bh = blockIdx.x;
    const int tid = threadIdx.x;
    ushort* kvb = kvT + (size_t)bh * KVT_STRIDE;
    for (int idx = tid; idx < 8192; idx += 256) {
        float s = 0.f;
#pragma unroll
        for (int c = 0; c < 8; ++c)
            s += kv_part[((size_t)(c * 32 + bh)) * 8192 + idx];
        kvb[idx] = f2bf(s);
    }
    if (tid < 128) {
        float s = 0.f;
#pragma unroll
        for (int c = 0; c < 8; ++c)
            s += sum_part[(size_t)(c * 32 + bh) * 128 + tid];
        const ushort hi = f2bf(s);
        const float lo = s - bf2f(hi);
        kvb[64 * 128 + tid] = hi;
        kvb[65 * 128 + tid] = f2bf(lo);
    }
    for (int idx = tid; idx < 14 * 128; idx += 256)
        kvb[66 * 128 + idx] = 0;
}

// ---------------- attention via MFMA: num = [qc|qs] @ kv, den as 5th col-tile ----------------
__global__ __launch_bounds__(256) void attn_kernel(
    const ushort* __restrict__ Qc, const ushort* __restrict__ Qs,
    const ushort* __restrict__ kvT,
    ushort* __restrict__ attn_out)
{
    const int bh = blockIdx.y;
    const int b = bh >> 3, h = bh & 7;
    const int tid = threadIdx.x;
    const int lane = tid & 63;
    const int w = tid >> 6;

    __shared__ ushort Bs[KVT_ROWS][136];

#pragma unroll
    for (int i = 0; i < 5; ++i) {
        const int c = i * 256 + tid;
        const int d = c >> 4, cc = c & 15;
        *reinterpret_cast<uint4*>(&Bs[d][cc * 8]) =
            *reinterpret_cast<const uint4*>(&kvT[(size_t)bh * KVT_STRIDE + (size_t)c * 8]);
    }
    __syncthreads();

    const int rowBase = blockIdx.x * 256 + w * 64;
    const int fr = lane & 15;
    const int g = lane >> 4;

    f32x4 acc[4][5];
#pragma unroll
    for (int m = 0; m < 4; ++m)
#pragma unroll
        for (int n = 0; n < 5; ++n)
            acc[m][n] = (f32x4){0.f, 0.f, 0.f, 0.f};

#pragma unroll
    for (int ks = 0; ks < 4; ++ks) {
        const ushort* __restrict__ src = (ks < 2) ? Qc : Qs;
        const int kk = (ks & 1) * 32 + g * 8;
        const int kcomb = ks * 32 + g * 8;

        bf16x8 af[4];
#pragma unroll
        for (int m = 0; m < 4; ++m) {
            const int r = rowBase + m * 16 + fr;
            af[m] = *reinterpret_cast<const bf16x8*>(
                &src[((size_t)(b * L_SEQ) + r) * E_DIM + h * DHEAD + kk]);
        }

        bf16x8 bfr[5];
#pragma unroll
        for (int n = 0; n < 5; ++n)
            bfr[n] = *reinterpret_cast<const bf16x8*>(&Bs[n * 16 + fr][kcomb]);
#pragma unroll
        for (int m = 0; m < 4; ++m)
#pragma unroll
            for (int n = 0; n < 5; ++n)
                acc[m][n] = __builtin_amdgcn_mfma_f32_16x16x32_bf16(af[m], bfr[n], acc[m][n], 0, 0, 0);
    }

#pragma unroll
    for (int m = 0; m < 4; ++m) {
#pragma unroll
        for (int j = 0; j < 4; ++j) {
            const float den = __shfl(acc[m][4][j], g * 16 + 0) + __shfl(acc[m][4][j], g * 16 + 1);
            const float z = 1.f / fmaxf(den, 1e-6f);
            const int grow = rowBase + m * 16 + g * 4 + j;
            const size_t obase = ((size_t)(b * L_SEQ) + grow) * E_DIM + h * DHEAD;
#pragma unroll
            for (int n = 0; n < 4; ++n)
                attn_out[obase + n * 16 + fr] = f2bf(acc[m][n][j] * z);
        }
    }
}

// ---------------- launch ----------------
extern "C" void kernel_launch(void* const* d_in, const int* in_sizes, int n_in,
                              void* d_out, int out_size, void* d_ws, size_t ws_size,
                              hipStream_t stream) {
    const float* x  = (const float*)d_in[0];
    const float* Wq = (const float*)d_in[1];
    const float* bq = (const float*)d_in[2];
    const float* Wk = (const float*)d_in[3];
    const float* bk = (const float*)d_in[4];
    const float* Wv = (const float*)d_in[5];
    const float* bv = (const float*)d_in[6];
    const float* Wo = (const float*)d_in[7];
    const float* bo = (const float*)d_in[8];
    float* out = (float*)d_out;

    char* ws = (char*)d_ws;
    size_t off = 0;
    auto alloc = [&](size_t bytes) -> char* {
        char* p = ws + off;
        off += (bytes + 255) & ~(size_t)255;
        return p;
    };

    const size_t big = (size_t)NROWS * E_DIM * sizeof(ushort);   // 16.8 MB
    ushort* xb  = (ushort*)alloc(big);
    ushort* wqb = (ushort*)alloc(512 * 512 * sizeof(ushort));
    ushort* wkb = (ushort*)alloc(512 * 512 * sizeof(ushort));
    ushort* wvb = (ushort*)alloc(512 * 512 * sizeof(ushort));
    ushort* wob = (ushort*)alloc(512 * 512 * sizeof(ushort));
    ushort* qc  = (ushort*)alloc(big);
    ushort* qs  = (ushort*)alloc(big);
    ushort* kcT = (ushort*)alloc(big);   // [bh][k][l]
    ushort* ksT = (ushort*)alloc(big);   // [bh][k][l]
    ushort* vT  = (ushort*)alloc(big);   // [bh][d][l]
    float* kv_part  = (float*)alloc((size_t)8 * 32 * 8192 * sizeof(float));
    float* sum_part = (float*)alloc((size_t)8 * 32 * 128 * sizeof(float));
    ushort* kvT     = (ushort*)alloc((size_t)32 * KVT_STRIDE * sizeof(ushort));
    float* sintab   = (float*)alloc(L_SEQ * sizeof(float));
    float* costab   = (float*)alloc(L_SEQ * sizeof(float));
    ushort* attnb = kcT;  // kcT fully consumed by kv_kernel before attn_kernel writes

    convert_kernel<<<2048, 256, 0, stream>>>(x, xb, NROWS * E_DIM / 4);
    convert_w_kernel<<<dim3(256, 5), 256, 0, stream>>>(
        Wq, Wk, Wv, Wo, wqb, wkb, wvb, wob, sintab, costab);

    qkv_kernel<<<dim3(128, 12), 256, 0, stream>>>(
        xb, wqb, wkb, wvb, bq, bk, bv, sintab, costab, qc, qs, kcT, ksT, vT);

    kv_kernel<<<dim3(8, 32), 256, 0, stream>>>(kcT, ksT, vT, kv_part, sum_part);
    kv_reduce_kernel<<<32, 256, 0, stream>>>(kv_part, sum_part, kvT);

    attn_kernel<<<dim3(16, 32), 256, 0, stream>>>(qc, qs, kvT, attnb);

    out_gemm_kernel<<<dim3(128, 4), 256, 0, stream>>>(attnb, wob, bo, out);
}

// Round 7
// 111.928 us; speedup vs baseline: 4.0398x; 1.0632x over previous
//
#include <hip/hip_runtime.h>
#include <hip/hip_bf16.h>

#define L_SEQ 4096
#define E_DIM 512
#define NHEAD 8
#define DHEAD 64
#define NBATCH 4
#define NROWS (NBATCH * L_SEQ)   // 16384

typedef short bf16x8 __attribute__((ext_vector_type(8)));
typedef float f32x4 __attribute__((ext_vector_type(4)));

__device__ __forceinline__ float bf2f(ushort u) {
    union { float f; unsigned int i; } x;
    x.i = ((unsigned int)u) << 16;
    return x.f;
}
__device__ __forceinline__ ushort f2bf(float f) {
    unsigned int u = __float_as_uint(f);
    unsigned int r = 0x7fffu + ((u >> 16) & 1u);
    u += r;
    return (ushort)(u >> 16);
}

#define GLD16(gptr, lptr) \
    __builtin_amdgcn_global_load_lds( \
        (const __attribute__((address_space(1))) void*)(gptr), \
        (__attribute__((address_space(3))) void*)(lptr), 16, 0, 0)

// ---------------- fp32 -> bf16 conversion (x) ----------------
__global__ void convert_kernel(const float* __restrict__ in, ushort* __restrict__ out, int n4) {
    int stride = gridDim.x * blockDim.x;
    for (int i = blockIdx.x * blockDim.x + threadIdx.x; i < n4; i += stride) {
        float4 f = reinterpret_cast<const float4*>(in)[i];
        ushort4 o;
        o.x = f2bf(f.x); o.y = f2bf(f.y); o.z = f2bf(f.z); o.w = f2bf(f.w);
        reinterpret_cast<ushort4*>(out)[i] = o;
    }
}

// ---------------- weights conversion + sin/cos tables, one dispatch ----------------
__global__ __launch_bounds__(256) void convert_w_kernel(
    const float* __restrict__ w0, const float* __restrict__ w1,
    const float* __restrict__ w2, const float* __restrict__ w3,
    ushort* __restrict__ o0, ushort* __restrict__ o1,
    ushort* __restrict__ o2, ushort* __restrict__ o3,
    float* __restrict__ sintab, float* __restrict__ costab)
{
    const int tid = threadIdx.x;
    const int y = blockIdx.y;
    if (y == 4) {
        const int l = blockIdx.x * 256 + tid;
        if (blockIdx.x < 16) {
            const float ang = (float)(l + 1) * (1.5707963267948966f / (float)L_SEQ);
            sintab[l] = sinf(ang);
            costab[l] = cosf(ang);
        }
        return;
    }
    const float* in = (y == 0) ? w0 : (y == 1) ? w1 : (y == 2) ? w2 : w3;
    ushort* out = (y == 0) ? o0 : (y == 1) ? o1 : (y == 2) ? o2 : o3;
    const int i = blockIdx.x * 256 + tid;
    float4 f = reinterpret_cast<const float4*>(in)[i];
    ushort4 o;
    o.x = f2bf(f.x); o.y = f2bf(f.y); o.z = f2bf(f.z); o.w = f2bf(f.w);
    reinterpret_cast<ushort4*>(out)[i] = o;
}

// ---------------- unified pipelined GEMM: 128x256 tile, BK=64, dbuf, counted vmcnt ----
// mode = modeBase + (blockIdx.y>>1); colBase = (blockIdx.y&1)*256
// mode 0 (Q):  relu; qc = v*cos, qs = v*sin               (normal [l][e] layout)
// mode 1 (K):  relu; kcT[bh][k][l] = v*cos, ksT = v*sin   (transposed via TS)
// mode 2 (V):  vT[bh][d][l] = v                           (transposed via TS)
// mode 3 (O):  outF = v + bias                            (fp32 normal layout)
// 8 waves (2M x 4N), wave output 64x64, acc[4][4]. LDS: 2 x (A 16KB + B 32KB) = 96KB.
// XOR swizzle (verified r6): store chunk ch at slot ch, source chunk ch^(row&7);
// read slot (kk*4+g)^(fr&7). Schedule: reads -> lgkmcnt0 -> barA -> stage(t+2)
// -> MFMA -> vmcnt(6) -> barB.  vmcnt(0) only at t==6.
__global__ __launch_bounds__(512) void gemm2_kernel(
    int modeBase,
    const ushort* __restrict__ xA, const ushort* __restrict__ oA,
    const ushort* __restrict__ wq, const ushort* __restrict__ wk,
    const ushort* __restrict__ wv, const ushort* __restrict__ wo,
    const float* __restrict__ bq, const float* __restrict__ bk,
    const float* __restrict__ bv, const float* __restrict__ bo,
    const float* __restrict__ sintab, const float* __restrict__ costab,
    ushort* __restrict__ qc, ushort* __restrict__ qs,
    ushort* __restrict__ kcT, ushort* __restrict__ ksT, ushort* __restrict__ vT,
    float* __restrict__ outF)
{
    __shared__ ushort SH[49152];   // 96KB: [cur*24576] A(8192) | B(16384); TS overlay

    const int tid = threadIdx.x;
    const int lane = tid & 63;
    const int wid = tid >> 6;
    const int wm = wid >> 2;          // 0..1  (64-row slice)
    const int wn = wid & 3;           // 0..3  (64-col slice)
    const int mode = modeBase + (blockIdx.y >> 1);
    const int colBase = (blockIdx.y & 1) * 256;
    const int rowBase = blockIdx.x * 128;

    const ushort* __restrict__ A = (mode == 3) ? oA : xA;
    const ushort* __restrict__ W = (mode == 0) ? wq : (mode == 1) ? wk : (mode == 2) ? wv : wo;
    const float* __restrict__ bias = (mode == 0) ? bq : (mode == 1) ? bk : (mode == 2) ? bv : bo;

    const int fr = lane & 15;
    const int g = lane >> 4;
    const int fr7 = fr & 7;

    // staging thread->chunk maps (row/chunk fixed per thread)
    const int sc_row = tid >> 3;          // 0..63  (c>>3 for c = i*512+tid)
    const int sc_ch  = tid & 7;
    // per-i rows: A rows i*64 + sc_row (i 0..1); B rows i*64 + sc_row (i 0..3)

    f32x4 acc[4][4];
#pragma unroll
    for (int m = 0; m < 4; ++m)
#pragma unroll
        for (int n = 0; n < 4; ++n)
            acc[m][n] = (f32x4){0.f, 0.f, 0.f, 0.f};

    auto STAGE = [&](int kt, int bufb) {
        const int k0 = kt * 64;
#pragma unroll
        for (int i = 0; i < 2; ++i) {
            const int row = i * 64 + sc_row;
            const int srcc = (sc_ch ^ (row & 7)) * 8;
            GLD16(&A[(size_t)(rowBase + row) * E_DIM + k0 + srcc],
                  &SH[bufb + (i * 512 + tid) * 8]);
        }
#pragma unroll
        for (int i = 0; i < 4; ++i) {
            const int row = i * 64 + sc_row;
            const int srcc = (sc_ch ^ (row & 7)) * 8;
            GLD16(&W[(size_t)(colBase + row) * E_DIM + k0 + srcc],
                  &SH[bufb + 8192 + (i * 512 + tid) * 8]);
        }
    };

    // prologue: stage kt0 -> buf0, kt1 -> buf1
    STAGE(0, 0);
    STAGE(1, 24576);
    asm volatile("s_waitcnt vmcnt(6)" ::: "memory");
    __builtin_amdgcn_sched_barrier(0);
    __builtin_amdgcn_s_barrier();
    __builtin_amdgcn_sched_barrier(0);

    const int kch0 = (g ^ fr7) * 8;            // kk=0 slot
    const int kch1 = ((4 + g) ^ fr7) * 8;      // kk=1 slot
    const int aroff = (wm * 64 + fr) * 64;     // + m*1024
    const int broff = 8192 + (wn * 64 + fr) * 64;

    for (int t = 0; t < 8; ++t) {
        const int base = (t & 1) * 24576;
        bf16x8 af[2][4], bfv[2][4];
#pragma unroll
        for (int m = 0; m < 4; ++m) {
            af[0][m] = *reinterpret_cast<const bf16x8*>(&SH[base + aroff + m * 1024 + kch0]);
            af[1][m] = *reinterpret_cast<const bf16x8*>(&SH[base + aroff + m * 1024 + kch1]);
        }
#pragma unroll
        for (int n = 0; n < 4; ++n) {
            bfv[0][n] = *reinterpret_cast<const bf16x8*>(&SH[base + broff + n * 1024 + kch0]);
            bfv[1][n] = *reinterpret_cast<const bf16x8*>(&SH[base + broff + n * 1024 + kch1]);
        }
        asm volatile("s_waitcnt lgkmcnt(0)" ::: "memory");
        __builtin_amdgcn_sched_barrier(0);
        __builtin_amdgcn_s_barrier();          // barrier A: all waves done reading buf
        __builtin_amdgcn_sched_barrier(0);

        if (t + 2 < 8) STAGE(t + 2, base);     // overwrite same buf, flies under MFMA

        __builtin_amdgcn_s_setprio(1);
#pragma unroll
        for (int kk = 0; kk < 2; ++kk)
#pragma unroll
            for (int m = 0; m < 4; ++m)
#pragma unroll
                for (int n = 0; n < 4; ++n)
                    acc[m][n] = __builtin_amdgcn_mfma_f32_16x16x32_bf16(
                        af[kk][m], bfv[kk][n], acc[m][n], 0, 0, 0);
        __builtin_amdgcn_s_setprio(0);
        __builtin_amdgcn_sched_barrier(0);

        if (t < 7) {
            if (t < 6) asm volatile("s_waitcnt vmcnt(6)" ::: "memory");
            else       asm volatile("s_waitcnt vmcnt(0)" ::: "memory");
            __builtin_amdgcn_sched_barrier(0);
            __builtin_amdgcn_s_barrier();      // barrier B: next buf ready
            __builtin_amdgcn_sched_barrier(0);
        }
    }

    // ---------------- epilogues ----------------
    if (mode == 0) {
#pragma unroll
        for (int m = 0; m < 4; ++m) {
#pragma unroll
            for (int j = 0; j < 4; ++j) {
                const int grow = rowBase + wm * 64 + m * 16 + g * 4 + j;
                const int l = grow & (L_SEQ - 1);
                const float cv = costab[l], sv = sintab[l];
#pragma unroll
                for (int n = 0; n < 4; ++n) {
                    const int gcol = colBase + wn * 64 + n * 16 + fr;
                    float val = fmaxf(acc[m][n][j] + bias[gcol], 0.f);
                    const size_t oidx = (size_t)grow * E_DIM + gcol;
                    qc[oidx] = f2bf(val * cv);
                    qs[oidx] = f2bf(val * sv);
                }
            }
        }
    } else if (mode == 3) {
#pragma unroll
        for (int m = 0; m < 4; ++m) {
#pragma unroll
            for (int j = 0; j < 4; ++j) {
                const int grow = rowBase + wm * 64 + m * 16 + g * 4 + j;
#pragma unroll
                for (int n = 0; n < 4; ++n) {
                    const int gcol = colBase + wn * 64 + n * 16 + fr;
                    outF[(size_t)grow * E_DIM + gcol] = acc[m][n][j] + bias[gcol];
                }
            }
        }
    } else {
        // transposed epilogue: scatter to TS[feat 256][l 128 +8 pad] (69.6KB overlay)
        ushort* TS = SH;
#pragma unroll
        for (int m = 0; m < 4; ++m) {
#pragma unroll
            for (int j = 0; j < 4; ++j) {
                const int lr_ = wm * 64 + m * 16 + g * 4 + j;     // local l 0..127
#pragma unroll
                for (int n = 0; n < 4; ++n) {
                    const int fc_ = wn * 64 + n * 16 + fr;        // local feat 0..255
                    float val = acc[m][n][j] + bias[colBase + fc_];
                    if (mode == 1) val = fmaxf(val, 0.f);
                    TS[fc_ * 136 + lr_] = f2bf(val);
                }
            }
        }
        __syncthreads();
        const int b = rowBase >> 12;
        const int lloc = rowBase & (L_SEQ - 1);
#pragma unroll
        for (int i = 0; i < 8; ++i) {
            const int c = i * 512 + tid;       // 4096 chunks: feat 256 x 16
            const int r = c >> 4;              // local feature 0..255
            const int cc = c & 15;             // 16B chunk along l (128 l = 16 chunks)
            const int gfeat = colBase + r;
            const size_t dst = ((size_t)(b * E_DIM + gfeat)) * L_SEQ + lloc + cc * 8;
            uint4 raw = *reinterpret_cast<const uint4*>(&TS[r * 136 + cc * 8]);
            if (mode == 2) {
                *reinterpret_cast<uint4*>(&vT[dst]) = raw;
            } else {
                ushort u[8] = {
                    (ushort)(raw.x & 0xffffu), (ushort)(raw.x >> 16),
                    (ushort)(raw.y & 0xffffu), (ushort)(raw.y >> 16),
                    (ushort)(raw.z & 0xffffu), (ushort)(raw.z >> 16),
                    (ushort)(raw.w & 0xffffu), (ushort)(raw.w >> 16)};
                const int lbase = lloc + cc * 8;
                float4 cv0 = *reinterpret_cast<const float4*>(&costab[lbase]);
                float4 cv1 = *reinterpret_cast<const float4*>(&costab[lbase + 4]);
                float4 sv0 = *reinterpret_cast<const float4*>(&sintab[lbase]);
                float4 sv1 = *reinterpret_cast<const float4*>(&sintab[lbase + 4]);
                const float cvv[8] = {cv0.x, cv0.y, cv0.z, cv0.w, cv1.x, cv1.y, cv1.z, cv1.w};
                const float svv[8] = {sv0.x, sv0.y, sv0.z, sv0.w, sv1.x, sv1.y, sv1.z, sv1.w};
                ushort uc[8], us[8];
#pragma unroll
                for (int e = 0; e < 8; ++e) {
                    const float v = bf2f(u[e]);
                    uc[e] = f2bf(v * cvv[e]);
                    us[e] = f2bf(v * svv[e]);
                }
                uint4 oc, os;
                oc.x = (uint)uc[0] | ((uint)uc[1] << 16); oc.y = (uint)uc[2] | ((uint)uc[3] << 16);
                oc.z = (uint)uc[4] | ((uint)uc[5] << 16); oc.w = (uint)uc[6] | ((uint)uc[7] << 16);
                os.x = (uint)us[0] | ((uint)us[1] << 16); os.y = (uint)us[2] | ((uint)us[3] << 16);
                os.z = (uint)us[4] | ((uint)us[5] << 16); os.w = (uint)us[6] | ((uint)us[7] << 16);
                *reinterpret_cast<uint4*>(&kcT[dst]) = oc;
                *reinterpret_cast<uint4*>(&ksT[dst]) = os;
            }
        }
    }
}

// ---------------- kv via MFMA, no LDS, no barriers ----------------
__global__ __launch_bounds__(256) void kv_kernel(
    const ushort* __restrict__ kcT, const ushort* __restrict__ ksT, const ushort* __restrict__ vT,
    float* __restrict__ kv_part, float* __restrict__ sum_part)
{
    const int chunk = blockIdx.x;   // 0..7
    const int bh = blockIdx.y;      // 0..31
    const int tid = threadIdx.x;
    const int lane = tid & 63;
    const int w = tid >> 6;
    const int fr = lane & 15;
    const int g = lane >> 4;

    const size_t tbase = (size_t)bh * 64 * L_SEQ;

    f32x4 acc[8], accS[8];
#pragma unroll
    for (int n = 0; n < 8; ++n) {
        acc[n] = (f32x4){0.f, 0.f, 0.f, 0.f};
        accS[n] = (f32x4){0.f, 0.f, 0.f, 0.f};
    }
    bf16x8 ones;
#pragma unroll
    for (int j = 0; j < 8; ++j) ones[j] = (short)0x3F80;

    const int lchunk = chunk * (L_SEQ / 8);
    for (int l0 = lchunk; l0 < lchunk + (L_SEQ / 8); l0 += 32) {
        const int col = l0 + g * 8;
        bf16x8 af = *reinterpret_cast<const bf16x8*>(&vT[tbase + (size_t)(w * 16 + fr) * L_SEQ + col]);
        bf16x8 bc[4], bs[4];
#pragma unroll
        for (int n = 0; n < 4; ++n) {
            bc[n] = *reinterpret_cast<const bf16x8*>(&kcT[tbase + (size_t)(n * 16 + fr) * L_SEQ + col]);
            bs[n] = *reinterpret_cast<const bf16x8*>(&ksT[tbase + (size_t)(n * 16 + fr) * L_SEQ + col]);
        }
#pragma unroll
        for (int n = 0; n < 4; ++n) {
            acc[n]      = __builtin_amdgcn_mfma_f32_16x16x32_bf16(af, bc[n], acc[n], 0, 0, 0);
            acc[n + 4]  = __builtin_amdgcn_mfma_f32_16x16x32_bf16(af, bs[n], acc[n + 4], 0, 0, 0);
            accS[n]     = __builtin_amdgcn_mfma_f32_16x16x32_bf16(ones, bc[n], accS[n], 0, 0, 0);
            accS[n + 4] = __builtin_amdgcn_mfma_f32_16x16x32_bf16(ones, bs[n], accS[n + 4], 0, 0, 0);
        }
    }

    const size_t pbase = ((size_t)(chunk * 32 + bh)) * 8192;
#pragma unroll
    for (int n = 0; n < 8; ++n)
#pragma unroll
        for (int j = 0; j < 4; ++j)
            kv_part[pbase + (size_t)(w * 16 + g * 4 + j) * 128 + n * 16 + fr] = acc[n][j];
    if (w == 0 && g == 0) {
        const size_t sbase = (size_t)(chunk * 32 + bh) * 128;
#pragma unroll
        for (int n = 0; n < 8; ++n)
            sum_part[sbase + n * 16 + fr] = accS[n][0];
    }
}

// ---------------- reduce partials; emit bf16 kvT_ext[bh][80][128] ----------------
#define KVT_ROWS 80
#define KVT_STRIDE (KVT_ROWS * 128)
__global__ __launch_bounds__(256) void kv_reduce_kernel(
    const float* __restrict__ kv_part, const float* __restrict__ sum_part,
    ushort* __restrict__ kvT)
{
    const int bh = blockIdx.x;
    const int tid = threadIdx.x;
    ushort* kvb = kvT + (size_t)bh * KVT_STRIDE;
    for (int idx = tid; idx < 8192; idx += 256) {
        float s = 0.f;
#pragma unroll
        for (int c = 0; c < 8; ++c)
            s += kv_part[((size_t)(c * 32 + bh)) * 8192 + idx];
        kvb[idx] = f2bf(s);
    }
    if (tid < 128) {
        float s = 0.f;
#pragma unroll
        for (int c = 0; c < 8; ++c)
            s += sum_part[(size_t)(c * 32 + bh) * 128 + tid];
        const ushort hi = f2bf(s);
        const float lo = s - bf2f(hi);
        kvb[64 * 128 + tid] = hi;
        kvb[65 * 128 + tid] = f2bf(lo);
    }
    for (int idx = tid; idx < 14 * 128; idx += 256)
        kvb[66 * 128 + idx] = 0;
}

// ---------------- attention via MFMA: num = [qc|qs] @ kv, den as 5th col-tile ----------------
__global__ __launch_bounds__(256) void attn_kernel(
    const ushort* __restrict__ Qc, const ushort* __restrict__ Qs,
    const ushort* __restrict__ kvT,
    ushort* __restrict__ attn_out)
{
    const int bh = blockIdx.y;
    const int b = bh >> 3, h = bh & 7;
    const int tid = threadIdx.x;
    const int lane = tid & 63;
    const int w = tid >> 6;

    __shared__ ushort Bs[KVT_ROWS][136];

#pragma unroll
    for (int i = 0; i < 5; ++i) {
        const int c = i * 256 + tid;
        const int d = c >> 4, cc = c & 15;
        *reinterpret_cast<uint4*>(&Bs[d][cc * 8]) =
            *reinterpret_cast<const uint4*>(&kvT[(size_t)bh * KVT_STRIDE + (size_t)c * 8]);
    }
    __syncthreads();

    const int rowBase = blockIdx.x * 256 + w * 64;
    const int fr = lane & 15;
    const int g = lane >> 4;

    f32x4 acc[4][5];
#pragma unroll
    for (int m = 0; m < 4; ++m)
#pragma unroll
        for (int n = 0; n < 5; ++n)
            acc[m][n] = (f32x4){0.f, 0.f, 0.f, 0.f};

#pragma unroll
    for (int ks = 0; ks < 4; ++ks) {
        const ushort* __restrict__ src = (ks < 2) ? Qc : Qs;
        const int kk = (ks & 1) * 32 + g * 8;
        const int kcomb = ks * 32 + g * 8;

        bf16x8 af[4];
#pragma unroll
        for (int m = 0; m < 4; ++m) {
            const int r = rowBase + m * 16 + fr;
            af[m] = *reinterpret_cast<const bf16x8*>(
                &src[((size_t)(b * L_SEQ) + r) * E_DIM + h * DHEAD + kk]);
        }

        bf16x8 bfr[5];
#pragma unroll
        for (int n = 0; n < 5; ++n)
            bfr[n] = *reinterpret_cast<const bf16x8*>(&Bs[n * 16 + fr][kcomb]);
#pragma unroll
        for (int m = 0; m < 4; ++m)
#pragma unroll
            for (int n = 0; n < 5; ++n)
                acc[m][n] = __builtin_amdgcn_mfma_f32_16x16x32_bf16(af[m], bfr[n], acc[m][n], 0, 0, 0);
    }

#pragma unroll
    for (int m = 0; m < 4; ++m) {
#pragma unroll
        for (int j = 0; j < 4; ++j) {
            const float den = __shfl(acc[m][4][j], g * 16 + 0) + __shfl(acc[m][4][j], g * 16 + 1);
            const float z = 1.f / fmaxf(den, 1e-6f);
            const int grow = rowBase + m * 16 + g * 4 + j;
            const size_t obase = ((size_t)(b * L_SEQ) + grow) * E_DIM + h * DHEAD;
#pragma unroll
            for (int n = 0; n < 4; ++n)
                attn_out[obase + n * 16 + fr] = f2bf(acc[m][n][j] * z);
        }
    }
}

// ---------------- launch ----------------
extern "C" void kernel_launch(void* const* d_in, const int* in_sizes, int n_in,
                              void* d_out, int out_size, void* d_ws, size_t ws_size,
                              hipStream_t stream) {
    const float* x  = (const float*)d_in[0];
    const float* Wq = (const float*)d_in[1];
    const float* bq = (const float*)d_in[2];
    const float* Wk = (const float*)d_in[3];
    const float* bk = (const float*)d_in[4];
    const float* Wv = (const float*)d_in[5];
    const float* bv = (const float*)d_in[6];
    const float* Wo = (const float*)d_in[7];
    const float* bo = (const float*)d_in[8];
    float* out = (float*)d_out;

    char* ws = (char*)d_ws;
    size_t off = 0;
    auto alloc = [&](size_t bytes) -> char* {
        char* p = ws + off;
        off += (bytes + 255) & ~(size_t)255;
        return p;
    };

    const size_t big = (size_t)NROWS * E_DIM * sizeof(ushort);   // 16.8 MB
    ushort* xb  = (ushort*)alloc(big);
    ushort* wqb = (ushort*)alloc(512 * 512 * sizeof(ushort));
    ushort* wkb = (ushort*)alloc(512 * 512 * sizeof(ushort));
    ushort* wvb = (ushort*)alloc(512 * 512 * sizeof(ushort));
    ushort* wob = (ushort*)alloc(512 * 512 * sizeof(ushort));
    ushort* qc  = (ushort*)alloc(big);
    ushort* qs  = (ushort*)alloc(big);
    ushort* kcT = (ushort*)alloc(big);   // [bh][k][l]
    ushort* ksT = (ushort*)alloc(big);   // [bh][k][l]
    ushort* vT  = (ushort*)alloc(big);   // [bh][d][l]
    float* kv_part  = (float*)alloc((size_t)8 * 32 * 8192 * sizeof(float));
    float* sum_part = (float*)alloc((size_t)8 * 32 * 128 * sizeof(float));
    ushort* kvT     = (ushort*)alloc((size_t)32 * KVT_STRIDE * sizeof(ushort));
    float* sintab   = (float*)alloc(L_SEQ * sizeof(float));
    float* costab   = (float*)alloc(L_SEQ * sizeof(float));
    ushort* attnb = kcT;  // kcT fully consumed by kv_kernel before attn_kernel writes

    convert_kernel<<<2048, 256, 0, stream>>>(x, xb, NROWS * E_DIM / 4);
    convert_w_kernel<<<dim3(256, 5), 256, 0, stream>>>(
        Wq, Wk, Wv, Wo, wqb, wkb, wvb, wob, sintab, costab);

    // QKV: modes 0..2, 2 col-tiles each -> grid (128, 6), 768 blocks = 3 exact rounds
    gemm2_kernel<<<dim3(128, 6), 512, 0, stream>>>(
        0, xb, nullptr, wqb, wkb, wvb, wob, bq, bk, bv, bo,
        sintab, costab, qc, qs, kcT, ksT, vT, nullptr);

    kv_kernel<<<dim3(8, 32), 256, 0, stream>>>(kcT, ksT, vT, kv_part, sum_part);
    kv_reduce_kernel<<<32, 256, 0, stream>>>(kv_part, sum_part, kvT);

    attn_kernel<<<dim3(16, 32), 256, 0, stream>>>(qc, qs, kvT, attnb);

    // out GEMM: mode 3 -> grid (128, 2), 256 blocks = 1 round
    gemm2_kernel<<<dim3(128, 2), 512, 0, stream>>>(
        3, xb, attnb, wqb, wkb, wvb, wob, bq, bk, bv, bo,
        sintab, costab, nullptr, nullptr, nullptr, nullptr, nullptr, out);
}

// Round 8
// 111.001 us; speedup vs baseline: 4.0736x; 1.0084x over previous
//
#include <hip/hip_runtime.h>
#include <hip/hip_bf16.h>

#define L_SEQ 4096
#define E_DIM 512
#define NHEAD 8
#define DHEAD 64
#define NBATCH 4
#define NROWS (NBATCH * L_SEQ)   // 16384

typedef short bf16x8 __attribute__((ext_vector_type(8)));
typedef float f32x4 __attribute__((ext_vector_type(4)));

__device__ __forceinline__ float bf2f(ushort u) {
    union { float f; unsigned int i; } x;
    x.i = ((unsigned int)u) << 16;
    return x.f;
}
__device__ __forceinline__ ushort f2bf(float f) {
    unsigned int u = __float_as_uint(f);
    unsigned int r = 0x7fffu + ((u >> 16) & 1u);
    u += r;
    return (ushort)(u >> 16);
}

#define GLD16(gptr, lptr) \
    __builtin_amdgcn_global_load_lds( \
        (const __attribute__((address_space(1))) void*)(gptr), \
        (__attribute__((address_space(3))) void*)(lptr), 16, 0, 0)

#define BAR_LGKM() do { \
    asm volatile("s_waitcnt lgkmcnt(0)" ::: "memory"); \
    __builtin_amdgcn_sched_barrier(0); \
    __builtin_amdgcn_s_barrier(); \
    __builtin_amdgcn_sched_barrier(0); } while (0)

// ---------------- fp32 -> bf16 conversion (x) ----------------
__global__ void convert_kernel(const float* __restrict__ in, ushort* __restrict__ out, int n4) {
    int stride = gridDim.x * blockDim.x;
    for (int i = blockIdx.x * blockDim.x + threadIdx.x; i < n4; i += stride) {
        float4 f = reinterpret_cast<const float4*>(in)[i];
        ushort4 o;
        o.x = f2bf(f.x); o.y = f2bf(f.y); o.z = f2bf(f.z); o.w = f2bf(f.w);
        reinterpret_cast<ushort4*>(out)[i] = o;
    }
}

// ---------------- weights conversion + sin/cos tables ----------------
__global__ __launch_bounds__(256) void convert_w_kernel(
    const float* __restrict__ w0, const float* __restrict__ w1,
    const float* __restrict__ w2, const float* __restrict__ w3,
    ushort* __restrict__ o0, ushort* __restrict__ o1,
    ushort* __restrict__ o2, ushort* __restrict__ o3,
    float* __restrict__ sintab, float* __restrict__ costab)
{
    const int tid = threadIdx.x;
    const int y = blockIdx.y;
    if (y == 4) {
        const int l = blockIdx.x * 256 + tid;
        if (blockIdx.x < 16) {
            const float ang = (float)(l + 1) * (1.5707963267948966f / (float)L_SEQ);
            sintab[l] = sinf(ang);
            costab[l] = cosf(ang);
        }
        return;
    }
    const float* in = (y == 0) ? w0 : (y == 1) ? w1 : (y == 2) ? w2 : w3;
    ushort* out = (y == 0) ? o0 : (y == 1) ? o1 : (y == 2) ? o2 : o3;
    const int i = blockIdx.x * 256 + tid;
    float4 f = reinterpret_cast<const float4*>(in)[i];
    ushort4 o;
    o.x = f2bf(f.x); o.y = f2bf(f.y); o.z = f2bf(f.z); o.w = f2bf(f.w);
    reinterpret_cast<ushort4*>(out)[i] = o;
}

// ---------------- persistent pipelined GEMM: 128x256 tile, BK=64, dbuf --------------
// grid 256 blocks x 512 threads. Block p: rowBase=(p>>1)*128, colBase=(p&1)*256,
// loops nt tiles (modes modeBase..modeBase+nt-1) with continuous cross-tile prefetch.
// mode 0 (Q): relu -> qb (bf16 [l][e])           mode 1 (K): relu -> kT[bh][k][l]
// mode 2 (V): -> vT[bh][d][l]                    mode 3 (O): -> outF (fp32 [l][e])
// LDS: dbuf 2x(A 16KB|B 32KB)=96KB + TS[128][132]=33KB (separate region).
__global__ __launch_bounds__(512) void gemm3_kernel(
    int modeBase, int nt,
    const ushort* __restrict__ xA, const ushort* __restrict__ oA,
    const ushort* __restrict__ wq, const ushort* __restrict__ wk,
    const ushort* __restrict__ wv, const ushort* __restrict__ wo,
    const float* __restrict__ bq, const float* __restrict__ bk,
    const float* __restrict__ bv, const float* __restrict__ bo,
    ushort* __restrict__ qb, ushort* __restrict__ kT, ushort* __restrict__ vT,
    float* __restrict__ outF)
{
    __shared__ ushort SH[66048];        // 96KB bufs + 33KB TS
    ushort* TS = SH + 49152;

    const int tid = threadIdx.x;
    const int lane = tid & 63;
    const int wid = tid >> 6;
    const int wm = wid >> 2;
    const int wn = wid & 3;
    const int p = blockIdx.x;
    const int rowBase = (p >> 1) * 128;
    const int colBase = (p & 1) * 256;

    const ushort* __restrict__ Ap = (modeBase == 3) ? oA : xA;

    const int fr = lane & 15;
    const int g = lane >> 4;
    const int fr7 = fr & 7;
    const int sc_row = tid >> 3;
    const int sc_ch  = tid & 7;
    const int totKt = nt * 8;

    f32x4 acc[4][4];
#pragma unroll
    for (int m = 0; m < 4; ++m)
#pragma unroll
        for (int n = 0; n < 4; ++n)
            acc[m][n] = (f32x4){0.f, 0.f, 0.f, 0.f};

    auto STAGE = [&](int gt2) {
        const int mode = modeBase + (gt2 >> 3);
        const ushort* __restrict__ W =
            (mode == 0) ? wq : (mode == 1) ? wk : (mode == 2) ? wv : wo;
        const int k0 = (gt2 & 7) * 64;
        const int bufb = (gt2 & 1) * 24576;
#pragma unroll
        for (int i = 0; i < 2; ++i) {
            const int row = i * 64 + sc_row;
            const int srcc = (sc_ch ^ (row & 7)) * 8;
            GLD16(&Ap[(size_t)(rowBase + row) * E_DIM + k0 + srcc],
                  &SH[bufb + (i * 512 + tid) * 8]);
        }
#pragma unroll
        for (int i = 0; i < 4; ++i) {
            const int row = i * 64 + sc_row;
            const int srcc = (sc_ch ^ (row & 7)) * 8;
            GLD16(&W[(size_t)(colBase + row) * E_DIM + k0 + srcc],
                  &SH[bufb + 8192 + (i * 512 + tid) * 8]);
        }
    };

    STAGE(0);
    STAGE(1);
    asm volatile("s_waitcnt vmcnt(6)" ::: "memory");
    __builtin_amdgcn_sched_barrier(0);
    __builtin_amdgcn_s_barrier();
    __builtin_amdgcn_sched_barrier(0);

    const int kch0 = (g ^ fr7) * 8;
    const int kch1 = ((4 + g) ^ fr7) * 8;
    const int aroff = (wm * 64 + fr) * 64;
    const int broff = 8192 + (wn * 64 + fr) * 64;
    const int b = rowBase >> 12;
    const int lloc = rowBase & (L_SEQ - 1);

    for (int gt = 0; gt < totKt; ++gt) {
        const int base = (gt & 1) * 24576;
        bf16x8 af[2][4], bfv[2][4];
#pragma unroll
        for (int m = 0; m < 4; ++m) {
            af[0][m] = *reinterpret_cast<const bf16x8*>(&SH[base + aroff + m * 1024 + kch0]);
            af[1][m] = *reinterpret_cast<const bf16x8*>(&SH[base + aroff + m * 1024 + kch1]);
        }
#pragma unroll
        for (int n = 0; n < 4; ++n) {
            bfv[0][n] = *reinterpret_cast<const bf16x8*>(&SH[base + broff + n * 1024 + kch0]);
            bfv[1][n] = *reinterpret_cast<const bf16x8*>(&SH[base + broff + n * 1024 + kch1]);
        }
        BAR_LGKM();

        if (gt + 2 < totKt) STAGE(gt + 2);

        __builtin_amdgcn_s_setprio(1);
#pragma unroll
        for (int kk = 0; kk < 2; ++kk)
#pragma unroll
            for (int m = 0; m < 4; ++m)
#pragma unroll
                for (int n = 0; n < 4; ++n)
                    acc[m][n] = __builtin_amdgcn_mfma_f32_16x16x32_bf16(
                        af[kk][m], bfv[kk][n], acc[m][n], 0, 0, 0);
        __builtin_amdgcn_s_setprio(0);
        __builtin_amdgcn_sched_barrier(0);

        if ((gt & 7) == 7) {
            const int mode = modeBase + (gt >> 3);
            const float* __restrict__ bias =
                (mode == 0) ? bq : (mode == 1) ? bk : (mode == 2) ? bv : bo;
            if (mode == 0) {
#pragma unroll
                for (int m = 0; m < 4; ++m)
#pragma unroll
                    for (int j = 0; j < 4; ++j) {
                        const int grow = rowBase + wm * 64 + m * 16 + g * 4 + j;
#pragma unroll
                        for (int n = 0; n < 4; ++n) {
                            const int gcol = colBase + wn * 64 + n * 16 + fr;
                            const float val = fmaxf(acc[m][n][j] + bias[gcol], 0.f);
                            qb[(size_t)grow * E_DIM + gcol] = f2bf(val);
                        }
                    }
            } else if (mode == 3) {
#pragma unroll
                for (int m = 0; m < 4; ++m)
#pragma unroll
                    for (int j = 0; j < 4; ++j) {
                        const int grow = rowBase + wm * 64 + m * 16 + g * 4 + j;
#pragma unroll
                        for (int n = 0; n < 4; ++n) {
                            const int gcol = colBase + wn * 64 + n * 16 + fr;
                            outF[(size_t)grow * E_DIM + gcol] = acc[m][n][j] + bias[gcol];
                        }
                    }
            } else {
                ushort* __restrict__ dstbuf = (mode == 1) ? kT : vT;
#pragma unroll
                for (int ph = 0; ph < 2; ++ph) {
                    BAR_LGKM();
                    if ((wn >> 1) == ph) {
#pragma unroll
                        for (int m = 0; m < 4; ++m)
#pragma unroll
                            for (int j = 0; j < 4; ++j) {
                                const int lr_ = wm * 64 + m * 16 + g * 4 + j;
#pragma unroll
                                for (int n = 0; n < 4; ++n) {
                                    const int fcl = (wn & 1) * 64 + n * 16 + fr;
                                    float val = acc[m][n][j] + bias[colBase + ph * 128 + fcl];
                                    if (mode == 1) val = fmaxf(val, 0.f);
                                    TS[fcl * 132 + lr_] = f2bf(val);
                                }
                            }
                    }
                    BAR_LGKM();
#pragma unroll
                    for (int i = 0; i < 4; ++i) {
                        const int c = i * 512 + tid;
                        const int r = c >> 4;
                        const int cc = c & 15;
                        const int gfeat = colBase + ph * 128 + r;
                        const size_t dst = ((size_t)(b * E_DIM + gfeat)) * L_SEQ + lloc + cc * 8;
                        *reinterpret_cast<uint4*>(&dstbuf[dst]) =
                            *reinterpret_cast<const uint4*>(&TS[r * 132 + cc * 8]);
                    }
                }
            }
#pragma unroll
            for (int m = 0; m < 4; ++m)
#pragma unroll
                for (int n = 0; n < 4; ++n)
                    acc[m][n] = (f32x4){0.f, 0.f, 0.f, 0.f};
        }

        if (gt < totKt - 1) {
            if (gt + 2 < totKt) asm volatile("s_waitcnt vmcnt(6)" ::: "memory");
            else                asm volatile("s_waitcnt vmcnt(0)" ::: "memory");
            __builtin_amdgcn_sched_barrier(0);
            __builtin_amdgcn_s_barrier();
            __builtin_amdgcn_sched_barrier(0);
        }
    }
}

// ---------------- kv via MFMA, fused cos/sin from tables, no LDS ----------------
__global__ __launch_bounds__(256) void kv_kernel(
    const ushort* __restrict__ kT, const ushort* __restrict__ vT,
    const float* __restrict__ sintab, const float* __restrict__ costab,
    float* __restrict__ kv_part, float* __restrict__ sum_part)
{
    const int chunk = blockIdx.x;   // 0..7
    const int bh = blockIdx.y;      // 0..31
    const int tid = threadIdx.x;
    const int lane = tid & 63;
    const int w = tid >> 6;
    const int fr = lane & 15;
    const int g = lane >> 4;

    const size_t tbase = (size_t)bh * 64 * L_SEQ;

    f32x4 acc[8], accS[8];
#pragma unroll
    for (int n = 0; n < 8; ++n) {
        acc[n] = (f32x4){0.f, 0.f, 0.f, 0.f};
        accS[n] = (f32x4){0.f, 0.f, 0.f, 0.f};
    }

    const int lchunk = chunk * (L_SEQ / 8);
    for (int l0 = lchunk; l0 < lchunk + (L_SEQ / 8); l0 += 32) {
        const int col = l0 + g * 8;
        bf16x8 vf = *reinterpret_cast<const bf16x8*>(&vT[tbase + (size_t)(w * 16 + fr) * L_SEQ + col]);
        bf16x8 kf[4];
#pragma unroll
        for (int n = 0; n < 4; ++n)
            kf[n] = *reinterpret_cast<const bf16x8*>(&kT[tbase + (size_t)(n * 16 + fr) * L_SEQ + col]);
        float4 c0 = *reinterpret_cast<const float4*>(&costab[col]);
        float4 c1 = *reinterpret_cast<const float4*>(&costab[col + 4]);
        float4 s0 = *reinterpret_cast<const float4*>(&sintab[col]);
        float4 s1 = *reinterpret_cast<const float4*>(&sintab[col + 4]);
        const float c8[8] = {c0.x, c0.y, c0.z, c0.w, c1.x, c1.y, c1.z, c1.w};
        const float s8[8] = {s0.x, s0.y, s0.z, s0.w, s1.x, s1.y, s1.z, s1.w};
        bf16x8 afc, afs, cw, sw;
#pragma unroll
        for (int e = 0; e < 8; ++e) {
            const float v = bf2f((ushort)vf[e]);
            afc[e] = (short)f2bf(v * c8[e]);
            afs[e] = (short)f2bf(v * s8[e]);
            cw[e]  = (short)f2bf(c8[e]);
            sw[e]  = (short)f2bf(s8[e]);
        }
#pragma unroll
        for (int n = 0; n < 4; ++n) {
            acc[n]      = __builtin_amdgcn_mfma_f32_16x16x32_bf16(afc, kf[n], acc[n], 0, 0, 0);
            acc[n + 4]  = __builtin_amdgcn_mfma_f32_16x16x32_bf16(afs, kf[n], acc[n + 4], 0, 0, 0);
            accS[n]     = __builtin_amdgcn_mfma_f32_16x16x32_bf16(cw,  kf[n], accS[n], 0, 0, 0);
            accS[n + 4] = __builtin_amdgcn_mfma_f32_16x16x32_bf16(sw,  kf[n], accS[n + 4], 0, 0, 0);
        }
    }

    const size_t pbase = ((size_t)(chunk * 32 + bh)) * 8192;
#pragma unroll
    for (int n = 0; n < 8; ++n)
#pragma unroll
        for (int j = 0; j < 4; ++j)
            kv_part[pbase + (size_t)(w * 16 + g * 4 + j) * 128 + n * 16 + fr] = acc[n][j];
    if (w == 0 && g == 0) {
        const size_t sbase = (size_t)(chunk * 32 + bh) * 128;
#pragma unroll
        for (int n = 0; n < 8; ++n)
            sum_part[sbase + n * 16 + fr] = accS[n][0];
    }
}

// ---------------- reduce partials; emit bf16 kvT_ext[bh][80][128] ----------------
#define KVT_ROWS 80
#define KVT_STRIDE (KVT_ROWS * 128)
__global__ __launch_bounds__(256) void kv_reduce_kernel(
    const float* __restrict__ kv_part, const float* __restrict__ sum_part,
    ushort* __restrict__ kvT)
{
    const int bh = blockIdx.x;
    const int tid = threadIdx.x;
    ushort* kvb = kvT + (size_t)bh * KVT_STRIDE;
    for (int idx = tid; idx < 8192; idx += 256) {
        float s = 0.f;
#pragma unroll
        for (int c = 0; c < 8; ++c)
            s += kv_part[((size_t)(c * 32 + bh)) * 8192 + idx];
        kvb[idx] = f2bf(s);
    }
    if (tid < 128) {
        float s = 0.f;
#pragma unroll
        for (int c = 0; c < 8; ++c)
            s += sum_part[(size_t)(c * 32 + bh) * 128 + tid];
        const ushort hi = f2bf(s);
        const float lo = s - bf2f(hi);
        kvb[64 * 128 + tid] = hi;
        kvb[65 * 128 + tid] = f2bf(lo);
    }
    for (int idx = tid; idx < 14 * 128; idx += 256)
        kvb[66 * 128 + idx] = 0;
}

// ---------------- attention via MFMA: A-fragments scaled by cos/sin on the fly -------
__global__ __launch_bounds__(256) void attn_kernel(
    const ushort* __restrict__ Qb, const ushort* __restrict__ kvT,
    const float* __restrict__ sintab, const float* __restrict__ costab,
    ushort* __restrict__ attn_out)
{
    const int bh = blockIdx.y;
    const int b = bh >> 3, h = bh & 7;
    const int tid = threadIdx.x;
    const int lane = tid & 63;
    const int w = tid >> 6;

    __shared__ ushort Bs[KVT_ROWS][136];

#pragma unroll
    for (int i = 0; i < 5; ++i) {
        const int c = i * 256 + tid;
        const int d = c >> 4, cc = c & 15;
        *reinterpret_cast<uint4*>(&Bs[d][cc * 8]) =
            *reinterpret_cast<const uint4*>(&kvT[(size_t)bh * KVT_STRIDE + (size_t)c * 8]);
    }
    __syncthreads();

    const int rowBase = blockIdx.x * 256 + w * 64;
    const int fr = lane & 15;
    const int g = lane >> 4;

    float cvm[4], svm[4];
#pragma unroll
    for (int m = 0; m < 4; ++m) {
        const int l = (rowBase + m * 16 + fr) & (L_SEQ - 1);
        cvm[m] = costab[l];
        svm[m] = sintab[l];
    }

    f32x4 acc[4][5];
#pragma unroll
    for (int m = 0; m < 4; ++m)
#pragma unroll
        for (int n = 0; n < 5; ++n)
            acc[m][n] = (f32x4){0.f, 0.f, 0.f, 0.f};

#pragma unroll
    for (int ks = 0; ks < 4; ++ks) {
        const int kk = (ks & 1) * 32 + g * 8;
        const int kcomb = ks * 32 + g * 8;

        bf16x8 af[4];
#pragma unroll
        for (int m = 0; m < 4; ++m) {
            const int r = rowBase + m * 16 + fr;
            bf16x8 qf = *reinterpret_cast<const bf16x8*>(
                &Qb[((size_t)(b * L_SEQ) + r) * E_DIM + h * DHEAD + kk]);
            const float sc = (ks < 2) ? cvm[m] : svm[m];
#pragma unroll
            for (int e = 0; e < 8; ++e)
                af[m][e] = (short)f2bf(bf2f((ushort)qf[e]) * sc);
        }

        bf16x8 bfr[5];
#pragma unroll
        for (int n = 0; n < 5; ++n)
            bfr[n] = *reinterpret_cast<const bf16x8*>(&Bs[n * 16 + fr][kcomb]);
#pragma unroll
        for (int m = 0; m < 4; ++m)
#pragma unroll
            for (int n = 0; n < 5; ++n)
                acc[m][n] = __builtin_amdgcn_mfma_f32_16x16x32_bf16(af[m], bfr[n], acc[m][n], 0, 0, 0);
    }

#pragma unroll
    for (int m = 0; m < 4; ++m) {
#pragma unroll
        for (int j = 0; j < 4; ++j) {
            const float den = __shfl(acc[m][4][j], g * 16 + 0) + __shfl(acc[m][4][j], g * 16 + 1);
            const float z = 1.f / fmaxf(den, 1e-6f);
            const int grow = rowBase + m * 16 + g * 4 + j;
            const size_t obase = ((size_t)(b * L_SEQ) + grow) * E_DIM + h * DHEAD;
#pragma unroll
            for (int n = 0; n < 4; ++n)
                attn_out[obase + n * 16 + fr] = f2bf(acc[m][n][j] * z);
        }
    }
}

// ---------------- launch ----------------
extern "C" void kernel_launch(void* const* d_in, const int* in_sizes, int n_in,
                              void* d_out, int out_size, void* d_ws, size_t ws_size,
                              hipStream_t stream) {
    const float* x  = (const float*)d_in[0];
    const float* Wq = (const float*)d_in[1];
    const float* bq = (const float*)d_in[2];
    const float* Wk = (const float*)d_in[3];
    const float* bk = (const float*)d_in[4];
    const float* Wv = (const float*)d_in[5];
    const float* bv = (const float*)d_in[6];
    const float* Wo = (const float*)d_in[7];
    const float* bo = (const float*)d_in[8];
    float* out = (float*)d_out;

    char* ws = (char*)d_ws;
    size_t off = 0;
    auto alloc = [&](size_t bytes) -> char* {
        char* p = ws + off;
        off += (bytes + 255) & ~(size_t)255;
        return p;
    };

    const size_t big = (size_t)NROWS * E_DIM * sizeof(ushort);   // 16.8 MB
    ushort* xb  = (ushort*)alloc(big);
    ushort* wqb = (ushort*)alloc(512 * 512 * sizeof(ushort));
    ushort* wkb = (ushort*)alloc(512 * 512 * sizeof(ushort));
    ushort* wvb = (ushort*)alloc(512 * 512 * sizeof(ushort));
    ushort* wob = (ushort*)alloc(512 * 512 * sizeof(ushort));
    ushort* qb  = (ushort*)alloc(big);   // relu(q), [l][e]
    ushort* kT  = (ushort*)alloc(big);   // relu(k) transposed [bh][k][l]
    ushort* vT  = (ushort*)alloc(big);   // v transposed [bh][d][l]
    float* kv_part  = (float*)alloc((size_t)8 * 32 * 8192 * sizeof(float));
    float* sum_part = (float*)alloc((size_t)8 * 32 * 128 * sizeof(float));
    ushort* kvT     = (ushort*)alloc((size_t)32 * KVT_STRIDE * sizeof(ushort));
    float* sintab   = (float*)alloc(L_SEQ * sizeof(float));
    float* costab   = (float*)alloc(L_SEQ * sizeof(float));
    ushort* attnb = kT;  // kT consumed by kv_kernel before attn_kernel writes

    convert_kernel<<<2048, 256, 0, stream>>>(x, xb, NROWS * E_DIM / 4);
    convert_w_kernel<<<dim3(256, 5), 256, 0, stream>>>(
        Wq, Wk, Wv, Wo, wqb, wkb, wvb, wob, sintab, costab);

    // QKV: persistent, 256 blocks x 3 tiles (modes 0..2 at fixed row/col)
    gemm3_kernel<<<256, 512, 0, stream>>>(
        0, 3, xb, nullptr, wqb, wkb, wvb, wob, bq, bk, bv, bo,
        qb, kT, vT, nullptr);

    kv_kernel<<<dim3(8, 32), 256, 0, stream>>>(kT, vT, sintab, costab, kv_part, sum_part);
    kv_reduce_kernel<<<32, 256, 0, stream>>>(kv_part, sum_part, kvT);

    attn_kernel<<<dim3(16, 32), 256, 0, stream>>>(qb, kvT, sintab, costab, attnb);

    // out GEMM: mode 3, 256 blocks x 1 tile
    gemm3_kernel<<<256, 512, 0, stream>>>(
        3, 1, xb, attnb, wqb, wkb, wvb, wob, bq, bk, bv, bo,
        nullptr, nullptr, nullptr, out);
}